// Round 12
// baseline (325.113 us; speedup 1.0000x reference)
//
#include <hip/hip_runtime.h>
#include <math.h>

#define IN_DIM 256
#define EPS_BN 1e-5f
#define NS 16  // BN shadow-copy count (atomic contention spreader)

typedef __attribute__((ext_vector_type(8))) short short8v;  // 8 bf16 (4 VGPRs)
typedef __attribute__((ext_vector_type(4))) float f32x4;    // MFMA C/D

__device__ __forceinline__ float lrelu(float v) { return v > 0.f ? v : 0.2f * v; }

__device__ __forceinline__ unsigned short f2bf(float f) {
    unsigned int u = __float_as_uint(f);
    u += 0x7fffu + ((u >> 16) & 1u);
    return (unsigned short)(u >> 16);
}
__device__ __forceinline__ float bf2f(unsigned short s) {
    return __uint_as_float((unsigned int)s << 16);
}

// packed bf16-pair FMA: a.x += w*lo(pw), a.y += w*hi(pw)
__device__ __forceinline__ void bfma(float2& a, unsigned int pw, float w) {
    a.x = fmaf(__uint_as_float(pw << 16), w, a.x);
    a.y = fmaf(__uint_as_float(pw & 0xffff0000u), w, a.y);
}

__device__ __forceinline__ void gld16(const void* g, void* l) {
    __builtin_amdgcn_global_load_lds((const __attribute__((address_space(1))) void*)g,
                                     (__attribute__((address_space(3))) void*)l, 16, 0, 0);
}

__device__ __forceinline__ int edge_at(const void* ei, int is64, long long i) {
    if (is64) return (int)((const long long*)ei)[i];
    return ((const int*)ei)[i];
}

// per-wave local dtype detect: odd 32-bit words 1..127 all zero -> int64.
// Every wave reads the SAME words (L2-hot) -> consistent decision, no global flag.
__device__ __forceinline__ int edge_is64(const void* ei, int E_) {
    const unsigned int* w = (const unsigned int*)ei;
    int lane = threadIdx.x & 63;
    long long idx = 2LL * lane + 1;
    unsigned int v = (idx < 2LL * E_) ? w[idx] : 0u;
    return (__ballot(v != 0u) == 0ULL) ? 1 : 0;
}

// ---------- K1: x-cast + Wt transposes + degree count (independent, one launch) ----------
__global__ __launch_bounds__(256) void prep_count_kernel(const float* __restrict__ x,
                                                         unsigned short* __restrict__ xb,
                                                         long long n8,
                                                         const float* __restrict__ W1,
                                                         unsigned short* __restrict__ Wt1,
                                                         const float* __restrict__ W2,
                                                         unsigned short* __restrict__ Wt2,
                                                         const void* __restrict__ ei,
                                                         int* __restrict__ deg, int E_) {
    long long nbx = (n8 + 255) / 256;
    long long b = blockIdx.x;
    if (b < nbx) {  // x f32 -> bf16
        long long i = b * 256 + threadIdx.x;
        if (i < n8) {
            const float4* p = (const float4*)(x + i * 8);
            float4 v0 = p[0], v1 = p[1];
            ushort4 o0, o1;
            o0.x = f2bf(v0.x); o0.y = f2bf(v0.y); o0.z = f2bf(v0.z); o0.w = f2bf(v0.w);
            o1.x = f2bf(v1.x); o1.y = f2bf(v1.y); o1.z = f2bf(v1.z); o1.w = f2bf(v1.w);
            *(ushort4*)(xb + i * 8) = o0;
            *(ushort4*)(xb + i * 8 + 4) = o1;
        }
        return;
    }
    b -= nbx;
    if (b < 256) {  // Wt1[c][k] = bf16(W1[k][c]), 256x256
        int idx = (int)b * 256 + threadIdx.x;
        int c = idx >> 8, k = idx & 255;
        Wt1[idx] = f2bf(W1[(long long)k * 256 + c]);
        return;
    }
    b -= 256;
    if (b < 128) {  // Wt2[c][k] = bf16(W2[k][c]), 128x256
        int idx = (int)b * 256 + threadIdx.x;
        int c = idx >> 8, k = idx & 255;
        Wt2[idx] = f2bf(W2[(long long)k * 128 + c]);
        return;
    }
    b -= 128;
    // degree count
    int is64 = edge_is64(ei, E_);
    int i = (int)b * 256 + threadIdx.x;
    if (i < E_) {
        int d = edge_at(ei, is64, (long long)E_ + i);
        atomicAdd(&deg[d], 1);
    }
}

// ---------- K2: single-kernel scan (each block self-computes its base; deg L2-hot) ----------
__global__ __launch_bounds__(256) void scan_kernel(const int* __restrict__ deg,
                                                   int* __restrict__ rowptr,
                                                   int* __restrict__ ctr, int n, int nb) {
    __shared__ int sh[256];
    __shared__ int base_sh;
    int t = threadIdx.x;
    int b = blockIdx.x;
    int lim = b * 256;
    int s = 0;
    for (int j = t; j < lim; j += 256) s += deg[j];
    sh[t] = s;
    __syncthreads();
    for (int off = 128; off >= 1; off >>= 1) {
        if (t < off) sh[t] += sh[t + off];
        __syncthreads();
    }
    if (t == 0) base_sh = sh[0];
    __syncthreads();
    int i = lim + t;
    int d = (i < n) ? deg[i] : 0;
    sh[t] = d;
    __syncthreads();
    for (int off = 1; off < 256; off <<= 1) {
        int u = (t >= off) ? sh[t - off] : 0;
        __syncthreads();
        sh[t] += u;
        __syncthreads();
    }
    if (i < n) {
        int v = base_sh + sh[t] - d;
        rowptr[i] = v;
        ctr[i] = v;
    }
    if (b == nb - 1 && t == 255) rowptr[n] = base_sh + sh[255];
}

// ---------- shared GEMM body (round-8/10 proven schedule): 128 rows x 64 cols ----------
// B [64 cols][256 K] staged once (gld16, pre-swizzled src); A streamed per 64-K chunk.
// FUSEBN: A reg-staged with BN+ReLU. Epilogue: bf16 C + attn-coef atomics.
template <int NCOL, int NH, bool FUSEBN>
__device__ __forceinline__ void gemm_body(unsigned short* A_lds, unsigned short* B_lds,
                                          float* scs, float* shs,
                                          const unsigned short* __restrict__ Ab,
                                          const unsigned short* __restrict__ Wt,
                                          unsigned short* __restrict__ C,
                                          const float* __restrict__ att_s,
                                          const float* __restrict__ att_d,
                                          float* __restrict__ a_s,
                                          float* __restrict__ a_d, int M,
                                          int row0, int col0,
                                          const float* __restrict__ bnsh,
                                          const float* __restrict__ gamma,
                                          const float* __restrict__ beta) {
    const int t = threadIdx.x;
    const int w = t >> 6, l = t & 63;

    {
        const char* wb = (const char*)Wt + (size_t)col0 * 512;
#pragma unroll
        for (int it = 0; it < 8; ++it) {
            int q = w * 8 + it;
            int i = q * 64 + l;
            int r = i >> 5;
            int cs = (i & 31) ^ (r & 7);
            gld16(wb + (size_t)r * 512 + cs * 16, (char*)B_lds + q * 1024);
        }
    }

    short8v nxt[4];
    const char* ab = (const char*)Ab + (size_t)row0 * 512;

    if (FUSEBN) {
        {
            int c = t;
            float s = 0.f, q = 0.f;
#pragma unroll
            for (int sh = 0; sh < NS; sh++) { s += bnsh[sh * 512 + c]; q += bnsh[sh * 512 + 256 + c]; }
            float invN = 1.f / (float)M;
            float mu = s * invN;
            float var = q * invN - mu * mu;
            float sc = rsqrtf(var + EPS_BN) * gamma[c];
            scs[c] = sc;
            shs[c] = beta[c] - mu * sc;
        }
#pragma unroll
        for (int it = 0; it < 4; ++it) {
            int i = it * 256 + t;
            int r = i >> 3, g = i & 7;
            int gr = row0 + r;
            nxt[it] = (gr < M) ? *(const short8v*)(Ab + (size_t)gr * 256 + g * 8)
                               : (short8v)(short)0;
        }
        __syncthreads();
#pragma unroll
        for (int it = 0; it < 4; ++it) {
            int i = it * 256 + t;
            int r = i >> 3, g = i & 7;
            int kb = g * 8;
            float4 s0 = *(const float4*)&scs[kb], s1 = *(const float4*)&scs[kb + 4];
            float4 h0 = *(const float4*)&shs[kb], h1 = *(const float4*)&shs[kb + 4];
            short8v v = nxt[it];
            short8v ov;
            ov[0] = (short)f2bf(fmaxf(bf2f((unsigned short)v[0]) * s0.x + h0.x, 0.f));
            ov[1] = (short)f2bf(fmaxf(bf2f((unsigned short)v[1]) * s0.y + h0.y, 0.f));
            ov[2] = (short)f2bf(fmaxf(bf2f((unsigned short)v[2]) * s0.z + h0.z, 0.f));
            ov[3] = (short)f2bf(fmaxf(bf2f((unsigned short)v[3]) * s0.w + h0.w, 0.f));
            ov[4] = (short)f2bf(fmaxf(bf2f((unsigned short)v[4]) * s1.x + h1.x, 0.f));
            ov[5] = (short)f2bf(fmaxf(bf2f((unsigned short)v[5]) * s1.y + h1.y, 0.f));
            ov[6] = (short)f2bf(fmaxf(bf2f((unsigned short)v[6]) * s1.z + h1.z, 0.f));
            ov[7] = (short)f2bf(fmaxf(bf2f((unsigned short)v[7]) * s1.w + h1.w, 0.f));
            *(short8v*)((char*)A_lds + r * 128 + ((g ^ (r & 7)) << 4)) = ov;
        }
    } else {
#pragma unroll
        for (int it = 0; it < 4; ++it) {
            int q = w * 4 + it;
            int i = q * 64 + l;
            int r = i >> 3;
            int cs = (i & 7) ^ (r & 7);
            gld16(ab + (size_t)r * 512 + cs * 16, (char*)A_lds + q * 1024);
        }
    }
    __syncthreads();

    const int rl = l & 15, kg = l >> 4;
    f32x4 acc0[4], acc1[4];
#pragma unroll
    for (int i = 0; i < 4; ++i) { acc0[i] = (f32x4)(0.f); acc1[i] = (f32x4)(0.f); }

    const int ar0 = w * 32 + rl, ar1 = ar0 + 16;
    const int aswz = (ar0 & 7) << 4;

    for (int c = 0; c < 4; ++c) {
        if (FUSEBN && c < 3) {
#pragma unroll
            for (int it = 0; it < 4; ++it) {
                int i = it * 256 + t;
                int r = i >> 3, g = i & 7;
                int gr = row0 + r;
                nxt[it] = (gr < M) ? *(const short8v*)(Ab + (size_t)gr * 256 + (c + 1) * 64 + g * 8)
                                   : (short8v)(short)0;
            }
        }
#pragma unroll
        for (int s = 0; s < 2; ++s) {
            short8v a0 = *(const short8v*)((const char*)A_lds +
                          ((ar0 * 128 + s * 64 + kg * 16) ^ aswz));
            short8v a1 = *(const short8v*)((const char*)A_lds +
                          ((ar1 * 128 + s * 64 + kg * 16) ^ aswz));
#pragma unroll
            for (int ct = 0; ct < 4; ++ct) {
                int br = ct * 16 + rl;
                short8v bfr = *(const short8v*)((const char*)B_lds +
                               ((br * 512 + c * 128 + s * 64 + kg * 16) ^ ((br & 7) << 4)));
                acc0[ct] = __builtin_amdgcn_mfma_f32_16x16x32_bf16(a0, bfr, acc0[ct], 0, 0, 0);
                acc1[ct] = __builtin_amdgcn_mfma_f32_16x16x32_bf16(a1, bfr, acc1[ct], 0, 0, 0);
            }
        }
        __syncthreads();
        if (c < 3) {
            if (FUSEBN) {
#pragma unroll
                for (int it = 0; it < 4; ++it) {
                    int i = it * 256 + t;
                    int r = i >> 3, g = i & 7;
                    int kb = (c + 1) * 64 + g * 8;
                    float4 s0 = *(const float4*)&scs[kb], s1 = *(const float4*)&scs[kb + 4];
                    float4 h0 = *(const float4*)&shs[kb], h1 = *(const float4*)&shs[kb + 4];
                    short8v v = nxt[it];
                    short8v ov;
                    ov[0] = (short)f2bf(fmaxf(bf2f((unsigned short)v[0]) * s0.x + h0.x, 0.f));
                    ov[1] = (short)f2bf(fmaxf(bf2f((unsigned short)v[1]) * s0.y + h0.y, 0.f));
                    ov[2] = (short)f2bf(fmaxf(bf2f((unsigned short)v[2]) * s0.z + h0.z, 0.f));
                    ov[3] = (short)f2bf(fmaxf(bf2f((unsigned short)v[3]) * s0.w + h0.w, 0.f));
                    ov[4] = (short)f2bf(fmaxf(bf2f((unsigned short)v[4]) * s1.x + h1.x, 0.f));
                    ov[5] = (short)f2bf(fmaxf(bf2f((unsigned short)v[5]) * s1.y + h1.y, 0.f));
                    ov[6] = (short)f2bf(fmaxf(bf2f((unsigned short)v[6]) * s1.z + h1.z, 0.f));
                    ov[7] = (short)f2bf(fmaxf(bf2f((unsigned short)v[7]) * s1.w + h1.w, 0.f));
                    *(short8v*)((char*)A_lds + r * 128 + ((g ^ (r & 7)) << 4)) = ov;
                }
            } else {
#pragma unroll
                for (int it = 0; it < 4; ++it) {
                    int q = w * 4 + it;
                    int i = q * 64 + l;
                    int r = i >> 3;
                    int cs = (i & 7) ^ (r & 7);
                    gld16(ab + (size_t)r * 512 + (c + 1) * 128 + cs * 16, (char*)A_lds + q * 1024);
                }
            }
            __syncthreads();
        }
    }

#pragma unroll
    for (int ct = 0; ct < 4; ++ct) {
#pragma unroll
        for (int r = 0; r < 4; ++r) {
            int gr0 = row0 + w * 32 + kg * 4 + r;
            if (gr0 < M) C[(long long)gr0 * NCOL + col0 + ct * 16 + rl] = f2bf(acc0[ct][r]);
            int gr1 = gr0 + 16;
            if (gr1 < M) C[(long long)gr1 * NCOL + col0 + ct * 16 + rl] = f2bf(acc1[ct][r]);
        }
    }

    float asp0[4] = {}, adp0[4] = {}, asp1[4] = {}, adp1[4] = {};
#pragma unroll
    for (int ct = 0; ct < 4; ++ct) {
        int col = col0 + ct * 16 + rl;
        float vs = att_s[col], vd = att_d[col];
#pragma unroll
        for (int r = 0; r < 4; ++r) {
            asp0[r] += acc0[ct][r] * vs; adp0[r] += acc0[ct][r] * vd;
            asp1[r] += acc1[ct][r] * vs; adp1[r] += acc1[ct][r] * vd;
        }
    }
#pragma unroll
    for (int off = 1; off < 16; off <<= 1) {
#pragma unroll
        for (int r = 0; r < 4; ++r) {
            asp0[r] += __shfl_xor(asp0[r], off);
            adp0[r] += __shfl_xor(adp0[r], off);
            asp1[r] += __shfl_xor(asp1[r], off);
            adp1[r] += __shfl_xor(adp1[r], off);
        }
    }
    if (rl == 0) {
        int head = (NH == 2) ? (col0 >> 7) : 0;
#pragma unroll
        for (int r = 0; r < 4; ++r) {
            int gr0 = row0 + w * 32 + kg * 4 + r;
            if (gr0 < M) {
                atomicAdd(&a_s[gr0 * NH + head], asp0[r]);
                atomicAdd(&a_d[gr0 * NH + head], adp0[r]);
            }
            int gr1 = gr0 + 16;
            if (gr1 < M) {
                atomicAdd(&a_s[gr1 * NH + head], asp1[r]);
                atomicAdd(&a_d[gr1 * NH + head], adp1[r]);
            }
        }
    }
}

// ---------- K3: scatter (blocks [0,eb)) ‖ gemm layer-1 (blocks [eb, eb+391*4)) ----------
__global__ __launch_bounds__(256) void scatter_gemm1_kernel(const void* __restrict__ ei,
                                                            int* __restrict__ ctr,
                                                            int* __restrict__ srcs, int E_,
                                                            int eb, int gbx,
                                                            const unsigned short* __restrict__ xb,
                                                            const unsigned short* __restrict__ Wt1,
                                                            unsigned short* __restrict__ h1b,
                                                            const float* __restrict__ att_s,
                                                            const float* __restrict__ att_d,
                                                            float* __restrict__ a_s,
                                                            float* __restrict__ a_d, int M) {
    __shared__ __attribute__((aligned(16))) unsigned short B_lds[64 * 256];  // 32 KB
    __shared__ __attribute__((aligned(16))) unsigned short A_lds[128 * 64];  // 16 KB
    int b = blockIdx.x;
    if (b < eb) {
        int is64 = edge_is64(ei, E_);
        int i = b * 256 + threadIdx.x;
        if (i < E_) {
            int s = edge_at(ei, is64, i);
            int d = edge_at(ei, is64, (long long)E_ + i);
            int pos = atomicAdd(&ctr[d], 1);
            srcs[pos] = s;
        }
        return;
    }
    b -= eb;
    int bx = b % gbx;
    int by = b / gbx;
    gemm_body<256, 2, false>(A_lds, B_lds, (float*)A_lds, (float*)A_lds, xb, Wt1, h1b,
                             att_s, att_d, a_s, a_d, M, bx * 128, by * 64,
                             nullptr, nullptr, nullptr);
}

// ---------- gemm layer 2 (fused BN1+ReLU on A) ----------
__global__ __launch_bounds__(256) void gemm2_kernel(const unsigned short* __restrict__ Ab,
                                                    const unsigned short* __restrict__ Wt,
                                                    unsigned short* __restrict__ C,
                                                    const float* __restrict__ att_s,
                                                    const float* __restrict__ att_d,
                                                    float* __restrict__ a_s,
                                                    float* __restrict__ a_d, int M,
                                                    const float* __restrict__ bnsh,
                                                    const float* __restrict__ gamma,
                                                    const float* __restrict__ beta) {
    __shared__ __attribute__((aligned(16))) unsigned short B_lds[64 * 256];  // 32 KB
    __shared__ __attribute__((aligned(16))) unsigned short A_lds[128 * 64];  // 16 KB
    __shared__ float scs[256];
    __shared__ float shs[256];
    gemm_body<128, 1, true>(A_lds, B_lds, scs, shs, Ab, Wt, C, att_s, att_d, a_s, a_d,
                            M, blockIdx.x * 128, blockIdx.y * 64, bnsh, gamma, beta);
}

// ---------- aggregate layer 1: persistent waves + register BN partials + packed FMA ----------
__global__ __launch_bounds__(256) void aggregate1_kernel(const unsigned short* __restrict__ h,
                                                         const int* __restrict__ rowptr,
                                                         const int* __restrict__ srcs,
                                                         const float* __restrict__ a_s,
                                                         const float* __restrict__ a_d,
                                                         const float* __restrict__ bias,
                                                         unsigned short* __restrict__ out,
                                                         float* __restrict__ bnsh, int Nn) {
    __shared__ float sw_lds[4][256];
    const int t = threadIdx.x;
    const int wid = t >> 6, lane = t & 63;
    const int hh = (lane >> 4) & 1;
    const int eb = lane >> 5;
    const int colb = (lane & 31) * 8;
    float* wbase = sw_lds[wid];
    float2 bnsum2[4] = {}, bnsq2[4] = {};
    const int stride = gridDim.x * 4;

    for (int n = blockIdx.x * 4 + wid; n < Nn; n += stride) {
        int beg = rowptr[n], end = rowptr[n + 1];
        float2 adv = *(const float2*)&a_d[(size_t)n * 2];
        float ad0 = adv.x, ad1 = adv.y;
        float2 acc2[4] = {};
        float den = 0.f, m0 = -1e30f, m1 = -1e30f;

        for (int cb = beg; cb < end; cb += 64) {
            int cnt = end - cb; if (cnt > 64) cnt = 64;
            float e0 = -1e30f, e1 = -1e30f;
            int s_l = 0;
            if (lane < cnt) {
                s_l = srcs[cb + lane];
                float2 av = *(const float2*)&a_s[(size_t)s_l * 2];
                e0 = lrelu(av.x + ad0);
                e1 = lrelu(av.y + ad1);
            }
            float cm0 = e0, cm1 = e1;
            for (int off = 32; off >= 1; off >>= 1) {
                cm0 = fmaxf(cm0, __shfl_xor(cm0, off));
                cm1 = fmaxf(cm1, __shfl_xor(cm1, off));
            }
            if (cm0 > m0 || cm1 > m1) {
                float f0 = (cm0 > m0) ? __expf(m0 - cm0) : 1.f;
                float f1 = (cm1 > m1) ? __expf(m1 - cm1) : 1.f;
                m0 = fmaxf(m0, cm0); m1 = fmaxf(m1, cm1);
                float fo = hh ? f1 : f0;
#pragma unroll
                for (int j = 0; j < 4; j++) { acc2[j].x *= fo; acc2[j].y *= fo; }
                den *= fo;
            }
            if (lane < cnt) {
                *(float2*)&wbase[lane * 2] = make_float2(__int_as_float(s_l), __expf(e0 - m0));
                *(float2*)&wbase[128 + lane * 2] = make_float2(__int_as_float(s_l), __expf(e1 - m1));
            }
            int c = 0;
            for (; c + 8 <= cnt; c += 8) {
                float2 sw0 = *(const float2*)&wbase[hh * 128 + (c + eb) * 2];
                float2 sw1 = *(const float2*)&wbase[hh * 128 + (c + 2 + eb) * 2];
                float2 sw2 = *(const float2*)&wbase[hh * 128 + (c + 4 + eb) * 2];
                float2 sw3 = *(const float2*)&wbase[hh * 128 + (c + 6 + eb) * 2];
                uint4 p0 = *(const uint4*)(h + ((size_t)__float_as_int(sw0.x) << 8) + colb);
                uint4 p1 = *(const uint4*)(h + ((size_t)__float_as_int(sw1.x) << 8) + colb);
                uint4 p2 = *(const uint4*)(h + ((size_t)__float_as_int(sw2.x) << 8) + colb);
                uint4 p3 = *(const uint4*)(h + ((size_t)__float_as_int(sw3.x) << 8) + colb);
                den += sw0.y + sw1.y + sw2.y + sw3.y;
                bfma(acc2[0], p0.x, sw0.y); bfma(acc2[1], p0.y, sw0.y);
                bfma(acc2[2], p0.z, sw0.y); bfma(acc2[3], p0.w, sw0.y);
                bfma(acc2[0], p1.x, sw1.y); bfma(acc2[1], p1.y, sw1.y);
                bfma(acc2[2], p1.z, sw1.y); bfma(acc2[3], p1.w, sw1.y);
                bfma(acc2[0], p2.x, sw2.y); bfma(acc2[1], p2.y, sw2.y);
                bfma(acc2[2], p2.z, sw2.y); bfma(acc2[3], p2.w, sw2.y);
                bfma(acc2[0], p3.x, sw3.y); bfma(acc2[1], p3.y, sw3.y);
                bfma(acc2[2], p3.z, sw3.y); bfma(acc2[3], p3.w, sw3.y);
            }
            for (; c + 4 <= cnt; c += 4) {
                float2 sw0 = *(const float2*)&wbase[hh * 128 + (c + eb) * 2];
                float2 sw1 = *(const float2*)&wbase[hh * 128 + (c + 2 + eb) * 2];
                uint4 p0 = *(const uint4*)(h + ((size_t)__float_as_int(sw0.x) << 8) + colb);
                uint4 p1 = *(const uint4*)(h + ((size_t)__float_as_int(sw1.x) << 8) + colb);
                den += sw0.y + sw1.y;
                bfma(acc2[0], p0.x, sw0.y); bfma(acc2[1], p0.y, sw0.y);
                bfma(acc2[2], p0.z, sw0.y); bfma(acc2[3], p0.w, sw0.y);
                bfma(acc2[0], p1.x, sw1.y); bfma(acc2[1], p1.y, sw1.y);
                bfma(acc2[2], p1.z, sw1.y); bfma(acc2[3], p1.w, sw1.y);
            }
            for (; c < cnt; c += 2) {
                int e = c + eb;
                if (e < cnt) {
                    float2 sw0 = *(const float2*)&wbase[hh * 128 + e * 2];
                    uint4 p0 = *(const uint4*)(h + ((size_t)__float_as_int(sw0.x) << 8) + colb);
                    den += sw0.y;
                    bfma(acc2[0], p0.x, sw0.y); bfma(acc2[1], p0.y, sw0.y);
                    bfma(acc2[2], p0.z, sw0.y); bfma(acc2[3], p0.w, sw0.y);
                }
            }
        }
        den += __shfl_xor(den, 32);
#pragma unroll
        for (int j = 0; j < 4; j++) {
            acc2[j].x += __shfl_xor(acc2[j].x, 32);
            acc2[j].y += __shfl_xor(acc2[j].y, 32);
        }
        if (lane < 32) {
            float inv = 1.f / (den + 1e-16f);
            float4 b0 = *(const float4*)&bias[colb];
            float4 b1 = *(const float4*)&bias[colb + 4];
            float of[8];
            of[0] = acc2[0].x * inv + b0.x; of[1] = acc2[0].y * inv + b0.y;
            of[2] = acc2[1].x * inv + b0.z; of[3] = acc2[1].y * inv + b0.w;
            of[4] = acc2[2].x * inv + b1.x; of[5] = acc2[2].y * inv + b1.y;
            of[6] = acc2[3].x * inv + b1.z; of[7] = acc2[3].y * inv + b1.w;
            short8v o;
#pragma unroll
            for (int j = 0; j < 4; j++) {
                o[2 * j] = (short)f2bf(of[2 * j]);
                o[2 * j + 1] = (short)f2bf(of[2 * j + 1]);
                bnsum2[j].x += of[2 * j];     bnsum2[j].y += of[2 * j + 1];
                bnsq2[j].x += of[2 * j] * of[2 * j];
                bnsq2[j].y += of[2 * j + 1] * of[2 * j + 1];
            }
            *(short8v*)(out + ((size_t)n << 8) + colb) = o;
        }
    }

    __syncthreads();
    if (lane < 32) {
#pragma unroll
        for (int j = 0; j < 4; j++) {
            wbase[colb + 2 * j] = bnsum2[j].x;
            wbase[colb + 2 * j + 1] = bnsum2[j].y;
        }
    }
    __syncthreads();
    {
        int sh = (blockIdx.x & (NS - 1)) * 512;
        float s = sw_lds[0][t] + sw_lds[1][t] + sw_lds[2][t] + sw_lds[3][t];
        atomicAdd(&bnsh[sh + t], s);
    }
    __syncthreads();
    if (lane < 32) {
#pragma unroll
        for (int j = 0; j < 4; j++) {
            wbase[colb + 2 * j] = bnsq2[j].x;
            wbase[colb + 2 * j + 1] = bnsq2[j].y;
        }
    }
    __syncthreads();
    {
        int sh = (blockIdx.x & (NS - 1)) * 512;
        float q = sw_lds[0][t] + sw_lds[1][t] + sw_lds[2][t] + sw_lds[3][t];
        atomicAdd(&bnsh[sh + 256 + t], q);
    }
}

// ---------- aggregate layer 2: persistent waves + register BN partials + packed FMA ----------
__global__ __launch_bounds__(256) void aggregate2_kernel(const unsigned short* __restrict__ h,
                                                         const int* __restrict__ rowptr,
                                                         const int* __restrict__ srcs,
                                                         const float* __restrict__ a_s,
                                                         const float* __restrict__ a_d,
                                                         const float* __restrict__ bias,
                                                         float* __restrict__ out,
                                                         float* __restrict__ bnsh, int Nn) {
    __shared__ float sw_lds[4][128];
    const int t = threadIdx.x;
    const int wid = t >> 6, lane = t & 63;
    const int eo = lane >> 4;
    const int colb = (lane & 15) * 8;
    float* wbase = sw_lds[wid];
    float2 bnsum2[4] = {}, bnsq2[4] = {};
    const int stride = gridDim.x * 4;

    for (int n = blockIdx.x * 4 + wid; n < Nn; n += stride) {
        int beg = rowptr[n], end = rowptr[n + 1];
        float ad = a_d[n];
        float2 acc2[4] = {};
        float den = 0.f, m = -1e30f;

        for (int cb = beg; cb < end; cb += 64) {
            int cnt = end - cb; if (cnt > 64) cnt = 64;
            float e_ = -1e30f;
            int s_l = 0;
            if (lane < cnt) {
                s_l = srcs[cb + lane];
                e_ = lrelu(a_s[s_l] + ad);
            }
            float cm = e_;
            for (int off = 32; off >= 1; off >>= 1) cm = fmaxf(cm, __shfl_xor(cm, off));
            if (cm > m) {
                float f = __expf(m - cm);
                m = cm;
#pragma unroll
                for (int j = 0; j < 4; j++) { acc2[j].x *= f; acc2[j].y *= f; }
                den *= f;
            }
            if (lane < cnt)
                *(float2*)&wbase[lane * 2] = make_float2(__int_as_float(s_l), __expf(e_ - m));
            int c = 0;
            for (; c + 16 <= cnt; c += 16) {
                float2 sw0 = *(const float2*)&wbase[(c + eo) * 2];
                float2 sw1 = *(const float2*)&wbase[(c + 4 + eo) * 2];
                float2 sw2 = *(const float2*)&wbase[(c + 8 + eo) * 2];
                float2 sw3 = *(const float2*)&wbase[(c + 12 + eo) * 2];
                uint4 p0 = *(const uint4*)(h + ((size_t)__float_as_int(sw0.x) << 7) + colb);
                uint4 p1 = *(const uint4*)(h + ((size_t)__float_as_int(sw1.x) << 7) + colb);
                uint4 p2 = *(const uint4*)(h + ((size_t)__float_as_int(sw2.x) << 7) + colb);
                uint4 p3 = *(const uint4*)(h + ((size_t)__float_as_int(sw3.x) << 7) + colb);
                den += sw0.y + sw1.y + sw2.y + sw3.y;
                bfma(acc2[0], p0.x, sw0.y); bfma(acc2[1], p0.y, sw0.y);
                bfma(acc2[2], p0.z, sw0.y); bfma(acc2[3], p0.w, sw0.y);
                bfma(acc2[0], p1.x, sw1.y); bfma(acc2[1], p1.y, sw1.y);
                bfma(acc2[2], p1.z, sw1.y); bfma(acc2[3], p1.w, sw1.y);
                bfma(acc2[0], p2.x, sw2.y); bfma(acc2[1], p2.y, sw2.y);
                bfma(acc2[2], p2.z, sw2.y); bfma(acc2[3], p2.w, sw2.y);
                bfma(acc2[0], p3.x, sw3.y); bfma(acc2[1], p3.y, sw3.y);
                bfma(acc2[2], p3.z, sw3.y); bfma(acc2[3], p3.w, sw3.y);
            }
            for (; c + 8 <= cnt; c += 8) {
                float2 sw0 = *(const float2*)&wbase[(c + eo) * 2];
                float2 sw1 = *(const float2*)&wbase[(c + 4 + eo) * 2];
                uint4 p0 = *(const uint4*)(h + ((size_t)__float_as_int(sw0.x) << 7) + colb);
                uint4 p1 = *(const uint4*)(h + ((size_t)__float_as_int(sw1.x) << 7) + colb);
                den += sw0.y + sw1.y;
                bfma(acc2[0], p0.x, sw0.y); bfma(acc2[1], p0.y, sw0.y);
                bfma(acc2[2], p0.z, sw0.y); bfma(acc2[3], p0.w, sw0.y);
                bfma(acc2[0], p1.x, sw1.y); bfma(acc2[1], p1.y, sw1.y);
                bfma(acc2[2], p1.z, sw1.y); bfma(acc2[3], p1.w, sw1.y);
            }
            for (; c < cnt; c += 4) {
                int e = c + eo;
                if (e < cnt) {
                    float2 sw0 = *(const float2*)&wbase[e * 2];
                    uint4 p0 = *(const uint4*)(h + ((size_t)__float_as_int(sw0.x) << 7) + colb);
                    den += sw0.y;
                    bfma(acc2[0], p0.x, sw0.y); bfma(acc2[1], p0.y, sw0.y);
                    bfma(acc2[2], p0.z, sw0.y); bfma(acc2[3], p0.w, sw0.y);
                }
            }
        }
        den += __shfl_xor(den, 16);
        den += __shfl_xor(den, 32);
#pragma unroll
        for (int j = 0; j < 4; j++) {
            acc2[j].x += __shfl_xor(acc2[j].x, 16);
            acc2[j].x += __shfl_xor(acc2[j].x, 32);
            acc2[j].y += __shfl_xor(acc2[j].y, 16);
            acc2[j].y += __shfl_xor(acc2[j].y, 32);
        }
        if (lane < 16) {
            float inv = 1.f / (den + 1e-16f);
            float4 b0 = *(const float4*)&bias[colb];
            float4 b1 = *(const float4*)&bias[colb + 4];
            float of[8];
            of[0] = acc2[0].x * inv + b0.x; of[1] = acc2[0].y * inv + b0.y;
            of[2] = acc2[1].x * inv + b0.z; of[3] = acc2[1].y * inv + b0.w;
            of[4] = acc2[2].x * inv + b1.x; of[5] = acc2[2].y * inv + b1.y;
            of[6] = acc2[3].x * inv + b1.z; of[7] = acc2[3].y * inv + b1.w;
#pragma unroll
            for (int j = 0; j < 4; j++) {
                bnsum2[j].x += of[2 * j];     bnsum2[j].y += of[2 * j + 1];
                bnsq2[j].x += of[2 * j] * of[2 * j];
                bnsq2[j].y += of[2 * j + 1] * of[2 * j + 1];
            }
            float* ob = out + (size_t)n * 128 + colb;
            *(float4*)ob = make_float4(of[0], of[1], of[2], of[3]);
            *(float4*)(ob + 4) = make_float4(of[4], of[5], of[6], of[7]);
        }
    }

    __syncthreads();
    if (lane < 16) {
#pragma unroll
        for (int j = 0; j < 4; j++) {
            wbase[colb + 2 * j] = bnsum2[j].x;
            wbase[colb + 2 * j + 1] = bnsum2[j].y;
        }
    }
    __syncthreads();
    if (t < 128) {
        int sh = (blockIdx.x & (NS - 1)) * 256;
        float s = sw_lds[0][t] + sw_lds[1][t] + sw_lds[2][t] + sw_lds[3][t];
        atomicAdd(&bnsh[sh + t], s);
    }
    __syncthreads();
    if (lane < 16) {
#pragma unroll
        for (int j = 0; j < 4; j++) {
            wbase[colb + 2 * j] = bnsq2[j].x;
            wbase[colb + 2 * j + 1] = bnsq2[j].y;
        }
    }
    __syncthreads();
    if (t < 128) {
        int sh = (blockIdx.x & (NS - 1)) * 256;
        float q = sw_lds[0][t] + sw_lds[1][t] + sw_lds[2][t] + sw_lds[3][t];
        atomicAdd(&bnsh[sh + 128 + t], q);
    }
}

// ---------- final BN+ReLU on f32 output, stats from shadows ----------
__global__ __launch_bounds__(256) void bn_apply_final_kernel(float* __restrict__ x,
                                                             const float* __restrict__ bnsh,
                                                             const float* __restrict__ gamma,
                                                             const float* __restrict__ beta,
                                                             int Nn) {
    int t = threadIdx.x;
    int col = t & 127;
    float s = 0.f, q = 0.f;
#pragma unroll
    for (int sh = 0; sh < NS; sh++) { s += bnsh[sh * 256 + col]; q += bnsh[sh * 256 + 128 + col]; }
    float mu = s / (float)Nn;
    float var = q / (float)Nn - mu * mu;
    float sc = rsqrtf(var + EPS_BN) * gamma[col];
    float sh_ = beta[col] - mu * sc;
    int r0 = blockIdx.x * 2 + (t >> 7);
    int rs = gridDim.x * 2;
    for (int r = r0; r < Nn; r += rs) {
        size_t idx = (size_t)r * 128 + col;
        x[idx] = fmaxf(x[idx] * sc + sh_, 0.f);
    }
}

extern "C" void kernel_launch(void* const* d_in, const int* in_sizes, int n_in,
                              void* d_out, int out_size, void* d_ws, size_t ws_size,
                              hipStream_t stream) {
    const float* x        = (const float*)d_in[0];
    const void*  ei       = d_in[1];
    const float* W1       = (const float*)d_in[2];
    const float* att_src1 = (const float*)d_in[3];
    const float* att_dst1 = (const float*)d_in[4];
    const float* b1       = (const float*)d_in[5];
    const float* g1       = (const float*)d_in[6];
    const float* be1      = (const float*)d_in[7];
    const float* W2       = (const float*)d_in[8];
    const float* att_src2 = (const float*)d_in[9];
    const float* att_dst2 = (const float*)d_in[10];
    const float* b2       = (const float*)d_in[11];
    const float* g2       = (const float*)d_in[12];
    const float* be2      = (const float*)d_in[13];

    const int Nn = in_sizes[0] / IN_DIM;  // 50000
    const int E_ = in_sizes[1] / 2;       // 800000
    const int gb = (Nn + 127) / 128;      // 391 row-blocks
    const int Mpad = gb * 128 + 128;

    char* ws = (char*)d_ws;
    size_t o = 0;
    auto alloc = [&](size_t bytes) {
        size_t r = o;
        o += (bytes + 255) & ~(size_t)255;
        return r;
    };
    size_t z0 = o;
    int*   deg   = (int*)(ws + alloc((size_t)Nn * 4));
    float* as1   = (float*)(ws + alloc((size_t)Nn * 2 * 4));
    float* ad1   = (float*)(ws + alloc((size_t)Nn * 2 * 4));
    float* as2   = (float*)(ws + alloc((size_t)Nn * 4));
    float* ad2   = (float*)(ws + alloc((size_t)Nn * 4));
    float* bn1sh = (float*)(ws + alloc((size_t)NS * 512 * 4));
    float* bn2sh = (float*)(ws + alloc((size_t)NS * 256 * 4));
    size_t z1 = o;
    int*   rowptr = (int*)(ws + alloc((size_t)(Nn + 1) * 4));
    int*   ctr    = (int*)(ws + alloc((size_t)Nn * 4));
    int*   srcs   = (int*)(ws + alloc((size_t)E_ * 4));
    unsigned short* Wt1  = (unsigned short*)(ws + alloc((size_t)256 * 256 * 2));
    unsigned short* Wt2  = (unsigned short*)(ws + alloc((size_t)128 * 256 * 2));
    unsigned short* xb   = (unsigned short*)(ws + alloc((size_t)Mpad * 256 * 2));
    unsigned short* x2b0 = (unsigned short*)(ws + alloc((size_t)Nn * 256 * 2));
    unsigned short* h1b  = (unsigned short*)(ws + alloc((size_t)Nn * 256 * 2));
    unsigned short* h2b  = (unsigned short*)(ws + alloc((size_t)Nn * 128 * 2));
    float* outf = (float*)d_out;

    hipMemsetAsync(ws + z0, 0, z1 - z0, stream);

    long long n8 = (long long)Nn * 256 / 8;
    int eb = (E_ + 255) / 256;            // 3125
    int nsb = (Nn + 255) / 256;           // 196

    // K1: x-cast + Wt transposes + degree count (independent work, one launch)
    {
        long long grid = (n8 + 255) / 256 + 256 + 128 + eb;
        prep_count_kernel<<<(int)grid, 256, 0, stream>>>(x, xb, n8, W1, Wt1, W2, Wt2,
                                                         ei, deg, E_);
    }
    // K2: scan
    scan_kernel<<<nsb, 256, 0, stream>>>(deg, rowptr, ctr, Nn, nsb);
    // K3: scatter ‖ gemm layer-1 (independent; scatter hides under MFMA)
    scatter_gemm1_kernel<<<eb + gb * 4, 256, 0, stream>>>(ei, ctr, srcs, E_, eb, gb,
                                                          xb, Wt1, h1b, att_src1, att_dst1,
                                                          as1, ad1, Nn);

    const int agg_blocks = 2048;  // persistent grid-stride

    aggregate1_kernel<<<agg_blocks, 256, 0, stream>>>(h1b, rowptr, srcs, as1, ad1, b1, x2b0,
                                                      bn1sh, Nn);
    gemm2_kernel<<<dim3(gb, 2), 256, 0, stream>>>(x2b0, Wt2, h2b, att_src2, att_dst2,
                                                  as2, ad2, Nn, bn1sh, g1, be1);
    aggregate2_kernel<<<agg_blocks, 256, 0, stream>>>(h2b, rowptr, srcs, as2, ad2, b2, outf,
                                                      bn2sh, Nn);
    bn_apply_final_kernel<<<512, 256, 0, stream>>>(outf, bn2sh, g2, be2, Nn);
}

// Round 13
// 314.039 us; speedup vs baseline: 1.0353x; 1.0353x over previous
//
#include <hip/hip_runtime.h>
#include <math.h>

#define IN_DIM 256
#define EPS_BN 1e-5f
#define NS 16  // BN shadow-copy count (atomic contention spreader)

typedef __attribute__((ext_vector_type(8))) short short8v;  // 8 bf16 (4 VGPRs)
typedef __attribute__((ext_vector_type(4))) float f32x4;    // MFMA C/D

__device__ __forceinline__ float lrelu(float v) { return v > 0.f ? v : 0.2f * v; }

__device__ __forceinline__ unsigned short f2bf(float f) {
    unsigned int u = __float_as_uint(f);
    u += 0x7fffu + ((u >> 16) & 1u);
    return (unsigned short)(u >> 16);
}
__device__ __forceinline__ float bf2f(unsigned short s) {
    return __uint_as_float((unsigned int)s << 16);
}

// packed bf16-pair FMA: a.x += w*lo(pw), a.y += w*hi(pw)
__device__ __forceinline__ void bfma(float2& a, unsigned int pw, float w) {
    a.x = fmaf(__uint_as_float(pw << 16), w, a.x);
    a.y = fmaf(__uint_as_float(pw & 0xffff0000u), w, a.y);
}

__device__ __forceinline__ void gld16(const void* g, void* l) {
    __builtin_amdgcn_global_load_lds((const __attribute__((address_space(1))) void*)g,
                                     (__attribute__((address_space(3))) void*)l, 16, 0, 0);
}

__device__ __forceinline__ int edge_at(const void* ei, int is64, long long i) {
    if (is64) return (int)((const long long*)ei)[i];
    return ((const int*)ei)[i];
}

// per-wave local dtype detect: odd 32-bit words of first 64 entries all zero -> int64.
// Every wave reads the SAME words (L2-hot) -> consistent decision, no global flag.
__device__ __forceinline__ int edge_is64(const void* ei, int E_) {
    const unsigned int* w = (const unsigned int*)ei;
    int lane = threadIdx.x & 63;
    long long idx = 2LL * lane + 1;
    unsigned int v = (idx < 2LL * E_) ? w[idx] : 0u;
    return (__ballot(v != 0u) == 0ULL) ? 1 : 0;
}

// ---------- K1: x-cast + Wt transposes + degree count (homogeneous, no LDS) ----------
__global__ __launch_bounds__(256) void prep_count_kernel(const float* __restrict__ x,
                                                         unsigned short* __restrict__ xb,
                                                         long long n8,
                                                         const float* __restrict__ W1,
                                                         unsigned short* __restrict__ Wt1,
                                                         const float* __restrict__ W2,
                                                         unsigned short* __restrict__ Wt2,
                                                         const void* __restrict__ ei,
                                                         int* __restrict__ deg, int E_) {
    long long nbx = (n8 + 255) / 256;
    long long b = blockIdx.x;
    if (b < nbx) {  // x f32 -> bf16
        long long i = b * 256 + threadIdx.x;
        if (i < n8) {
            const float4* p = (const float4*)(x + i * 8);
            float4 v0 = p[0], v1 = p[1];
            ushort4 o0, o1;
            o0.x = f2bf(v0.x); o0.y = f2bf(v0.y); o0.z = f2bf(v0.z); o0.w = f2bf(v0.w);
            o1.x = f2bf(v1.x); o1.y = f2bf(v1.y); o1.z = f2bf(v1.z); o1.w = f2bf(v1.w);
            *(ushort4*)(xb + i * 8) = o0;
            *(ushort4*)(xb + i * 8 + 4) = o1;
        }
        return;
    }
    b -= nbx;
    if (b < 256) {  // Wt1[c][k] = bf16(W1[k][c]), 256x256
        int idx = (int)b * 256 + threadIdx.x;
        int c = idx >> 8, k = idx & 255;
        Wt1[idx] = f2bf(W1[(long long)k * 256 + c]);
        return;
    }
    b -= 256;
    if (b < 128) {  // Wt2[c][k] = bf16(W2[k][c]), 128x256
        int idx = (int)b * 256 + threadIdx.x;
        int c = idx >> 8, k = idx & 255;
        Wt2[idx] = f2bf(W2[(long long)k * 128 + c]);
        return;
    }
    b -= 128;
    // degree count
    int is64 = edge_is64(ei, E_);
    int i = (int)b * 256 + threadIdx.x;
    if (i < E_) {
        int d = edge_at(ei, is64, (long long)E_ + i);
        atomicAdd(&deg[d], 1);
    }
}

// ---------- K2: single-kernel scan (each block self-computes its base; deg L2-hot) ----------
__global__ __launch_bounds__(256) void scan_kernel(const int* __restrict__ deg,
                                                   int* __restrict__ rowptr,
                                                   int* __restrict__ ctr, int n, int nb) {
    __shared__ int sh[256];
    __shared__ int base_sh;
    int t = threadIdx.x;
    int b = blockIdx.x;
    int lim = b * 256;
    int s = 0;
    for (int j = t; j < lim; j += 256) s += deg[j];
    sh[t] = s;
    __syncthreads();
    for (int off = 128; off >= 1; off >>= 1) {
        if (t < off) sh[t] += sh[t + off];
        __syncthreads();
    }
    if (t == 0) base_sh = sh[0];
    __syncthreads();
    int i = lim + t;
    int d = (i < n) ? deg[i] : 0;
    sh[t] = d;
    __syncthreads();
    for (int off = 1; off < 256; off <<= 1) {
        int u = (t >= off) ? sh[t - off] : 0;
        __syncthreads();
        sh[t] += u;
        __syncthreads();
    }
    if (i < n) {
        int v = base_sh + sh[t] - d;
        rowptr[i] = v;
        ctr[i] = v;
    }
    if (b == nb - 1 && t == 255) rowptr[n] = base_sh + sh[255];
}

// ---------- K3: scatter srcs by dst ----------
__global__ void scatter_kernel(const void* __restrict__ ei,
                               int* __restrict__ ctr, int* __restrict__ srcs, int E_) {
    int is64 = edge_is64(ei, E_);
    int i = blockIdx.x * 256 + threadIdx.x;
    if (i < E_) {
        int s = edge_at(ei, is64, i);
        int d = edge_at(ei, is64, (long long)E_ + i);
        int pos = atomicAdd(&ctr[d], 1);
        srcs[pos] = s;
    }
}

// ---------- MFMA bf16 GEMM + fused attn-coef epilogue (+ optional fused BN on A) ----------
// Round-10 proven schedule: 128 rows x 64 cols; B staged once; A streamed per 64-K chunk.
template <int NCOL, int NH, bool FUSEBN>
__global__ __launch_bounds__(256) void gemm_mfma_kernel(const unsigned short* __restrict__ Ab,
                                                        const unsigned short* __restrict__ Wt,
                                                        unsigned short* __restrict__ C,
                                                        const float* __restrict__ att_s,
                                                        const float* __restrict__ att_d,
                                                        float* __restrict__ a_s,
                                                        float* __restrict__ a_d, int M,
                                                        const float* __restrict__ bnsh,
                                                        const float* __restrict__ gamma,
                                                        const float* __restrict__ beta) {
    __shared__ unsigned short B_lds[64 * 256];   // 32 KB
    __shared__ unsigned short A_lds[128 * 64];   // 16 KB
    __shared__ float scs[FUSEBN ? 256 : 1];
    __shared__ float shs[FUSEBN ? 256 : 1];
    const int t = threadIdx.x;
    const int w = t >> 6, l = t & 63;
    const int row0 = blockIdx.x * 128;
    const int col0 = blockIdx.y * 64;

    {
        const char* wb = (const char*)Wt + (size_t)col0 * 512;
#pragma unroll
        for (int it = 0; it < 8; ++it) {
            int q = w * 8 + it;
            int i = q * 64 + l;
            int r = i >> 5;
            int cs = (i & 31) ^ (r & 7);
            gld16(wb + (size_t)r * 512 + cs * 16, (char*)B_lds + q * 1024);
        }
    }

    short8v nxt[4];
    const char* ab = (const char*)Ab + (size_t)row0 * 512;

    if (FUSEBN) {
        {
            int c = t;
            float s = 0.f, q = 0.f;
#pragma unroll
            for (int sh = 0; sh < NS; sh++) { s += bnsh[sh * 512 + c]; q += bnsh[sh * 512 + 256 + c]; }
            float invN = 1.f / (float)M;
            float mu = s * invN;
            float var = q * invN - mu * mu;
            float sc = rsqrtf(var + EPS_BN) * gamma[c];
            scs[c] = sc;
            shs[c] = beta[c] - mu * sc;
        }
#pragma unroll
        for (int it = 0; it < 4; ++it) {
            int i = it * 256 + t;
            int r = i >> 3, g = i & 7;
            int gr = row0 + r;
            nxt[it] = (gr < M) ? *(const short8v*)(Ab + (size_t)gr * 256 + g * 8)
                               : (short8v)(short)0;
        }
        __syncthreads();
#pragma unroll
        for (int it = 0; it < 4; ++it) {
            int i = it * 256 + t;
            int r = i >> 3, g = i & 7;
            int kb = g * 8;
            float4 s0 = *(const float4*)&scs[kb], s1 = *(const float4*)&scs[kb + 4];
            float4 h0 = *(const float4*)&shs[kb], h1 = *(const float4*)&shs[kb + 4];
            short8v v = nxt[it];
            short8v ov;
            ov[0] = (short)f2bf(fmaxf(bf2f((unsigned short)v[0]) * s0.x + h0.x, 0.f));
            ov[1] = (short)f2bf(fmaxf(bf2f((unsigned short)v[1]) * s0.y + h0.y, 0.f));
            ov[2] = (short)f2bf(fmaxf(bf2f((unsigned short)v[2]) * s0.z + h0.z, 0.f));
            ov[3] = (short)f2bf(fmaxf(bf2f((unsigned short)v[3]) * s0.w + h0.w, 0.f));
            ov[4] = (short)f2bf(fmaxf(bf2f((unsigned short)v[4]) * s1.x + h1.x, 0.f));
            ov[5] = (short)f2bf(fmaxf(bf2f((unsigned short)v[5]) * s1.y + h1.y, 0.f));
            ov[6] = (short)f2bf(fmaxf(bf2f((unsigned short)v[6]) * s1.z + h1.z, 0.f));
            ov[7] = (short)f2bf(fmaxf(bf2f((unsigned short)v[7]) * s1.w + h1.w, 0.f));
            *(short8v*)((char*)A_lds + r * 128 + ((g ^ (r & 7)) << 4)) = ov;
        }
    } else {
#pragma unroll
        for (int it = 0; it < 4; ++it) {
            int q = w * 4 + it;
            int i = q * 64 + l;
            int r = i >> 3;
            int cs = (i & 7) ^ (r & 7);
            gld16(ab + (size_t)r * 512 + cs * 16, (char*)A_lds + q * 1024);
        }
    }
    __syncthreads();

    const int rl = l & 15, kg = l >> 4;
    f32x4 acc0[4], acc1[4];
#pragma unroll
    for (int i = 0; i < 4; ++i) { acc0[i] = (f32x4)(0.f); acc1[i] = (f32x4)(0.f); }

    const int ar0 = w * 32 + rl, ar1 = ar0 + 16;
    const int aswz = (ar0 & 7) << 4;

    for (int c = 0; c < 4; ++c) {
        if (FUSEBN && c < 3) {
#pragma unroll
            for (int it = 0; it < 4; ++it) {
                int i = it * 256 + t;
                int r = i >> 3, g = i & 7;
                int gr = row0 + r;
                nxt[it] = (gr < M) ? *(const short8v*)(Ab + (size_t)gr * 256 + (c + 1) * 64 + g * 8)
                                   : (short8v)(short)0;
            }
        }
#pragma unroll
        for (int s = 0; s < 2; ++s) {
            short8v a0 = *(const short8v*)((const char*)A_lds +
                          ((ar0 * 128 + s * 64 + kg * 16) ^ aswz));
            short8v a1 = *(const short8v*)((const char*)A_lds +
                          ((ar1 * 128 + s * 64 + kg * 16) ^ aswz));
#pragma unroll
            for (int ct = 0; ct < 4; ++ct) {
                int br = ct * 16 + rl;
                short8v bfr = *(const short8v*)((const char*)B_lds +
                               ((br * 512 + c * 128 + s * 64 + kg * 16) ^ ((br & 7) << 4)));
                acc0[ct] = __builtin_amdgcn_mfma_f32_16x16x32_bf16(a0, bfr, acc0[ct], 0, 0, 0);
                acc1[ct] = __builtin_amdgcn_mfma_f32_16x16x32_bf16(a1, bfr, acc1[ct], 0, 0, 0);
            }
        }
        __syncthreads();
        if (c < 3) {
            if (FUSEBN) {
#pragma unroll
                for (int it = 0; it < 4; ++it) {
                    int i = it * 256 + t;
                    int r = i >> 3, g = i & 7;
                    int kb = (c + 1) * 64 + g * 8;
                    float4 s0 = *(const float4*)&scs[kb], s1 = *(const float4*)&scs[kb + 4];
                    float4 h0 = *(const float4*)&shs[kb], h1 = *(const float4*)&shs[kb + 4];
                    short8v v = nxt[it];
                    short8v ov;
                    ov[0] = (short)f2bf(fmaxf(bf2f((unsigned short)v[0]) * s0.x + h0.x, 0.f));
                    ov[1] = (short)f2bf(fmaxf(bf2f((unsigned short)v[1]) * s0.y + h0.y, 0.f));
                    ov[2] = (short)f2bf(fmaxf(bf2f((unsigned short)v[2]) * s0.z + h0.z, 0.f));
                    ov[3] = (short)f2bf(fmaxf(bf2f((unsigned short)v[3]) * s0.w + h0.w, 0.f));
                    ov[4] = (short)f2bf(fmaxf(bf2f((unsigned short)v[4]) * s1.x + h1.x, 0.f));
                    ov[5] = (short)f2bf(fmaxf(bf2f((unsigned short)v[5]) * s1.y + h1.y, 0.f));
                    ov[6] = (short)f2bf(fmaxf(bf2f((unsigned short)v[6]) * s1.z + h1.z, 0.f));
                    ov[7] = (short)f2bf(fmaxf(bf2f((unsigned short)v[7]) * s1.w + h1.w, 0.f));
                    *(short8v*)((char*)A_lds + r * 128 + ((g ^ (r & 7)) << 4)) = ov;
                }
            } else {
#pragma unroll
                for (int it = 0; it < 4; ++it) {
                    int q = w * 4 + it;
                    int i = q * 64 + l;
                    int r = i >> 3;
                    int cs = (i & 7) ^ (r & 7);
                    gld16(ab + (size_t)r * 512 + (c + 1) * 128 + cs * 16, (char*)A_lds + q * 1024);
                }
            }
            __syncthreads();
        }
    }

#pragma unroll
    for (int ct = 0; ct < 4; ++ct) {
#pragma unroll
        for (int r = 0; r < 4; ++r) {
            int gr0 = row0 + w * 32 + kg * 4 + r;
            if (gr0 < M) C[(long long)gr0 * NCOL + col0 + ct * 16 + rl] = f2bf(acc0[ct][r]);
            int gr1 = gr0 + 16;
            if (gr1 < M) C[(long long)gr1 * NCOL + col0 + ct * 16 + rl] = f2bf(acc1[ct][r]);
        }
    }

    float asp0[4] = {}, adp0[4] = {}, asp1[4] = {}, adp1[4] = {};
#pragma unroll
    for (int ct = 0; ct < 4; ++ct) {
        int col = col0 + ct * 16 + rl;
        float vs = att_s[col], vd = att_d[col];
#pragma unroll
        for (int r = 0; r < 4; ++r) {
            asp0[r] += acc0[ct][r] * vs; adp0[r] += acc0[ct][r] * vd;
            asp1[r] += acc1[ct][r] * vs; adp1[r] += acc1[ct][r] * vd;
        }
    }
#pragma unroll
    for (int off = 1; off < 16; off <<= 1) {
#pragma unroll
        for (int r = 0; r < 4; ++r) {
            asp0[r] += __shfl_xor(asp0[r], off);
            adp0[r] += __shfl_xor(adp0[r], off);
            asp1[r] += __shfl_xor(asp1[r], off);
            adp1[r] += __shfl_xor(adp1[r], off);
        }
    }
    if (rl == 0) {
        int head = (NH == 2) ? (col0 >> 7) : 0;
#pragma unroll
        for (int r = 0; r < 4; ++r) {
            int gr0 = row0 + w * 32 + kg * 4 + r;
            if (gr0 < M) {
                atomicAdd(&a_s[gr0 * NH + head], asp0[r]);
                atomicAdd(&a_d[gr0 * NH + head], adp0[r]);
            }
            int gr1 = gr0 + 16;
            if (gr1 < M) {
                atomicAdd(&a_s[gr1 * NH + head], asp1[r]);
                atomicAdd(&a_d[gr1 * NH + head], adp1[r]);
            }
        }
    }
}

// ---------- aggregate layer 1: persistent waves + register BN partials + packed FMA ----------
__global__ __launch_bounds__(256) void aggregate1_kernel(const unsigned short* __restrict__ h,
                                                         const int* __restrict__ rowptr,
                                                         const int* __restrict__ srcs,
                                                         const float* __restrict__ a_s,
                                                         const float* __restrict__ a_d,
                                                         const float* __restrict__ bias,
                                                         unsigned short* __restrict__ out,
                                                         float* __restrict__ bnsh, int Nn) {
    __shared__ float sw_lds[4][256];
    const int t = threadIdx.x;
    const int wid = t >> 6, lane = t & 63;
    const int hh = (lane >> 4) & 1;
    const int eb = lane >> 5;
    const int colb = (lane & 31) * 8;
    float* wbase = sw_lds[wid];
    float2 bnsum2[4] = {}, bnsq2[4] = {};
    const int stride = gridDim.x * 4;

    for (int n = blockIdx.x * 4 + wid; n < Nn; n += stride) {
        int beg = rowptr[n], end = rowptr[n + 1];
        float2 adv = *(const float2*)&a_d[(size_t)n * 2];
        float ad0 = adv.x, ad1 = adv.y;
        float2 acc2[4] = {};
        float den = 0.f, m0 = -1e30f, m1 = -1e30f;

        for (int cb = beg; cb < end; cb += 64) {
            int cnt = end - cb; if (cnt > 64) cnt = 64;
            float e0 = -1e30f, e1 = -1e30f;
            int s_l = 0;
            if (lane < cnt) {
                s_l = srcs[cb + lane];
                float2 av = *(const float2*)&a_s[(size_t)s_l * 2];
                e0 = lrelu(av.x + ad0);
                e1 = lrelu(av.y + ad1);
            }
            float cm0 = e0, cm1 = e1;
            for (int off = 32; off >= 1; off >>= 1) {
                cm0 = fmaxf(cm0, __shfl_xor(cm0, off));
                cm1 = fmaxf(cm1, __shfl_xor(cm1, off));
            }
            if (cm0 > m0 || cm1 > m1) {
                float f0 = (cm0 > m0) ? __expf(m0 - cm0) : 1.f;
                float f1 = (cm1 > m1) ? __expf(m1 - cm1) : 1.f;
                m0 = fmaxf(m0, cm0); m1 = fmaxf(m1, cm1);
                float fo = hh ? f1 : f0;
#pragma unroll
                for (int j = 0; j < 4; j++) { acc2[j].x *= fo; acc2[j].y *= fo; }
                den *= fo;
            }
            if (lane < cnt) {
                *(float2*)&wbase[lane * 2] = make_float2(__int_as_float(s_l), __expf(e0 - m0));
                *(float2*)&wbase[128 + lane * 2] = make_float2(__int_as_float(s_l), __expf(e1 - m1));
            }
            int c = 0;
            for (; c + 8 <= cnt; c += 8) {
                float2 sw0 = *(const float2*)&wbase[hh * 128 + (c + eb) * 2];
                float2 sw1 = *(const float2*)&wbase[hh * 128 + (c + 2 + eb) * 2];
                float2 sw2 = *(const float2*)&wbase[hh * 128 + (c + 4 + eb) * 2];
                float2 sw3 = *(const float2*)&wbase[hh * 128 + (c + 6 + eb) * 2];
                uint4 p0 = *(const uint4*)(h + ((size_t)__float_as_int(sw0.x) << 8) + colb);
                uint4 p1 = *(const uint4*)(h + ((size_t)__float_as_int(sw1.x) << 8) + colb);
                uint4 p2 = *(const uint4*)(h + ((size_t)__float_as_int(sw2.x) << 8) + colb);
                uint4 p3 = *(const uint4*)(h + ((size_t)__float_as_int(sw3.x) << 8) + colb);
                den += sw0.y + sw1.y + sw2.y + sw3.y;
                bfma(acc2[0], p0.x, sw0.y); bfma(acc2[1], p0.y, sw0.y);
                bfma(acc2[2], p0.z, sw0.y); bfma(acc2[3], p0.w, sw0.y);
                bfma(acc2[0], p1.x, sw1.y); bfma(acc2[1], p1.y, sw1.y);
                bfma(acc2[2], p1.z, sw1.y); bfma(acc2[3], p1.w, sw1.y);
                bfma(acc2[0], p2.x, sw2.y); bfma(acc2[1], p2.y, sw2.y);
                bfma(acc2[2], p2.z, sw2.y); bfma(acc2[3], p2.w, sw2.y);
                bfma(acc2[0], p3.x, sw3.y); bfma(acc2[1], p3.y, sw3.y);
                bfma(acc2[2], p3.z, sw3.y); bfma(acc2[3], p3.w, sw3.y);
            }
            for (; c + 4 <= cnt; c += 4) {
                float2 sw0 = *(const float2*)&wbase[hh * 128 + (c + eb) * 2];
                float2 sw1 = *(const float2*)&wbase[hh * 128 + (c + 2 + eb) * 2];
                uint4 p0 = *(const uint4*)(h + ((size_t)__float_as_int(sw0.x) << 8) + colb);
                uint4 p1 = *(const uint4*)(h + ((size_t)__float_as_int(sw1.x) << 8) + colb);
                den += sw0.y + sw1.y;
                bfma(acc2[0], p0.x, sw0.y); bfma(acc2[1], p0.y, sw0.y);
                bfma(acc2[2], p0.z, sw0.y); bfma(acc2[3], p0.w, sw0.y);
                bfma(acc2[0], p1.x, sw1.y); bfma(acc2[1], p1.y, sw1.y);
                bfma(acc2[2], p1.z, sw1.y); bfma(acc2[3], p1.w, sw1.y);
            }
            for (; c < cnt; c += 2) {
                int e = c + eb;
                if (e < cnt) {
                    float2 sw0 = *(const float2*)&wbase[hh * 128 + e * 2];
                    uint4 p0 = *(const uint4*)(h + ((size_t)__float_as_int(sw0.x) << 8) + colb);
                    den += sw0.y;
                    bfma(acc2[0], p0.x, sw0.y); bfma(acc2[1], p0.y, sw0.y);
                    bfma(acc2[2], p0.z, sw0.y); bfma(acc2[3], p0.w, sw0.y);
                }
            }
        }
        den += __shfl_xor(den, 32);
#pragma unroll
        for (int j = 0; j < 4; j++) {
            acc2[j].x += __shfl_xor(acc2[j].x, 32);
            acc2[j].y += __shfl_xor(acc2[j].y, 32);
        }
        if (lane < 32) {
            float inv = 1.f / (den + 1e-16f);
            float4 b0 = *(const float4*)&bias[colb];
            float4 b1 = *(const float4*)&bias[colb + 4];
            float of[8];
            of[0] = acc2[0].x * inv + b0.x; of[1] = acc2[0].y * inv + b0.y;
            of[2] = acc2[1].x * inv + b0.z; of[3] = acc2[1].y * inv + b0.w;
            of[4] = acc2[2].x * inv + b1.x; of[5] = acc2[2].y * inv + b1.y;
            of[6] = acc2[3].x * inv + b1.z; of[7] = acc2[3].y * inv + b1.w;
            short8v o;
#pragma unroll
            for (int j = 0; j < 4; j++) {
                o[2 * j] = (short)f2bf(of[2 * j]);
                o[2 * j + 1] = (short)f2bf(of[2 * j + 1]);
                bnsum2[j].x += of[2 * j];     bnsum2[j].y += of[2 * j + 1];
                bnsq2[j].x += of[2 * j] * of[2 * j];
                bnsq2[j].y += of[2 * j + 1] * of[2 * j + 1];
            }
            *(short8v*)(out + ((size_t)n << 8) + colb) = o;
        }
    }

    // once-per-block BN reduction (reuse sw_lds)
    __syncthreads();
    if (lane < 32) {
#pragma unroll
        for (int j = 0; j < 4; j++) {
            wbase[colb + 2 * j] = bnsum2[j].x;
            wbase[colb + 2 * j + 1] = bnsum2[j].y;
        }
    }
    __syncthreads();
    {
        int sh = (blockIdx.x & (NS - 1)) * 512;
        float s = sw_lds[0][t] + sw_lds[1][t] + sw_lds[2][t] + sw_lds[3][t];
        atomicAdd(&bnsh[sh + t], s);
    }
    __syncthreads();
    if (lane < 32) {
#pragma unroll
        for (int j = 0; j < 4; j++) {
            wbase[colb + 2 * j] = bnsq2[j].x;
            wbase[colb + 2 * j + 1] = bnsq2[j].y;
        }
    }
    __syncthreads();
    {
        int sh = (blockIdx.x & (NS - 1)) * 512;
        float q = sw_lds[0][t] + sw_lds[1][t] + sw_lds[2][t] + sw_lds[3][t];
        atomicAdd(&bnsh[sh + 256 + t], q);
    }
}

// ---------- aggregate layer 2: persistent waves + register BN partials + packed FMA ----------
__global__ __launch_bounds__(256) void aggregate2_kernel(const unsigned short* __restrict__ h,
                                                         const int* __restrict__ rowptr,
                                                         const int* __restrict__ srcs,
                                                         const float* __restrict__ a_s,
                                                         const float* __restrict__ a_d,
                                                         const float* __restrict__ bias,
                                                         float* __restrict__ out,
                                                         float* __restrict__ bnsh, int Nn) {
    __shared__ float sw_lds[4][128];
    const int t = threadIdx.x;
    const int wid = t >> 6, lane = t & 63;
    const int eo = lane >> 4;
    const int colb = (lane & 15) * 8;
    float* wbase = sw_lds[wid];
    float2 bnsum2[4] = {}, bnsq2[4] = {};
    const int stride = gridDim.x * 4;

    for (int n = blockIdx.x * 4 + wid; n < Nn; n += stride) {
        int beg = rowptr[n], end = rowptr[n + 1];
        float ad = a_d[n];
        float2 acc2[4] = {};
        float den = 0.f, m = -1e30f;

        for (int cb = beg; cb < end; cb += 64) {
            int cnt = end - cb; if (cnt > 64) cnt = 64;
            float e_ = -1e30f;
            int s_l = 0;
            if (lane < cnt) {
                s_l = srcs[cb + lane];
                e_ = lrelu(a_s[s_l] + ad);
            }
            float cm = e_;
            for (int off = 32; off >= 1; off >>= 1) cm = fmaxf(cm, __shfl_xor(cm, off));
            if (cm > m) {
                float f = __expf(m - cm);
                m = cm;
#pragma unroll
                for (int j = 0; j < 4; j++) { acc2[j].x *= f; acc2[j].y *= f; }
                den *= f;
            }
            if (lane < cnt)
                *(float2*)&wbase[lane * 2] = make_float2(__int_as_float(s_l), __expf(e_ - m));
            int c = 0;
            for (; c + 16 <= cnt; c += 16) {
                float2 sw0 = *(const float2*)&wbase[(c + eo) * 2];
                float2 sw1 = *(const float2*)&wbase[(c + 4 + eo) * 2];
                float2 sw2 = *(const float2*)&wbase[(c + 8 + eo) * 2];
                float2 sw3 = *(const float2*)&wbase[(c + 12 + eo) * 2];
                uint4 p0 = *(const uint4*)(h + ((size_t)__float_as_int(sw0.x) << 7) + colb);
                uint4 p1 = *(const uint4*)(h + ((size_t)__float_as_int(sw1.x) << 7) + colb);
                uint4 p2 = *(const uint4*)(h + ((size_t)__float_as_int(sw2.x) << 7) + colb);
                uint4 p3 = *(const uint4*)(h + ((size_t)__float_as_int(sw3.x) << 7) + colb);
                den += sw0.y + sw1.y + sw2.y + sw3.y;
                bfma(acc2[0], p0.x, sw0.y); bfma(acc2[1], p0.y, sw0.y);
                bfma(acc2[2], p0.z, sw0.y); bfma(acc2[3], p0.w, sw0.y);
                bfma(acc2[0], p1.x, sw1.y); bfma(acc2[1], p1.y, sw1.y);
                bfma(acc2[2], p1.z, sw1.y); bfma(acc2[3], p1.w, sw1.y);
                bfma(acc2[0], p2.x, sw2.y); bfma(acc2[1], p2.y, sw2.y);
                bfma(acc2[2], p2.z, sw2.y); bfma(acc2[3], p2.w, sw2.y);
                bfma(acc2[0], p3.x, sw3.y); bfma(acc2[1], p3.y, sw3.y);
                bfma(acc2[2], p3.z, sw3.y); bfma(acc2[3], p3.w, sw3.y);
            }
            for (; c + 8 <= cnt; c += 8) {
                float2 sw0 = *(const float2*)&wbase[(c + eo) * 2];
                float2 sw1 = *(const float2*)&wbase[(c + 4 + eo) * 2];
                uint4 p0 = *(const uint4*)(h + ((size_t)__float_as_int(sw0.x) << 7) + colb);
                uint4 p1 = *(const uint4*)(h + ((size_t)__float_as_int(sw1.x) << 7) + colb);
                den += sw0.y + sw1.y;
                bfma(acc2[0], p0.x, sw0.y); bfma(acc2[1], p0.y, sw0.y);
                bfma(acc2[2], p0.z, sw0.y); bfma(acc2[3], p0.w, sw0.y);
                bfma(acc2[0], p1.x, sw1.y); bfma(acc2[1], p1.y, sw1.y);
                bfma(acc2[2], p1.z, sw1.y); bfma(acc2[3], p1.w, sw1.y);
            }
            for (; c < cnt; c += 4) {
                int e = c + eo;
                if (e < cnt) {
                    float2 sw0 = *(const float2*)&wbase[e * 2];
                    uint4 p0 = *(const uint4*)(h + ((size_t)__float_as_int(sw0.x) << 7) + colb);
                    den += sw0.y;
                    bfma(acc2[0], p0.x, sw0.y); bfma(acc2[1], p0.y, sw0.y);
                    bfma(acc2[2], p0.z, sw0.y); bfma(acc2[3], p0.w, sw0.y);
                }
            }
        }
        den += __shfl_xor(den, 16);
        den += __shfl_xor(den, 32);
#pragma unroll
        for (int j = 0; j < 4; j++) {
            acc2[j].x += __shfl_xor(acc2[j].x, 16);
            acc2[j].x += __shfl_xor(acc2[j].x, 32);
            acc2[j].y += __shfl_xor(acc2[j].y, 16);
            acc2[j].y += __shfl_xor(acc2[j].y, 32);
        }
        if (lane < 16) {
            float inv = 1.f / (den + 1e-16f);
            float4 b0 = *(const float4*)&bias[colb];
            float4 b1 = *(const float4*)&bias[colb + 4];
            float of[8];
            of[0] = acc2[0].x * inv + b0.x; of[1] = acc2[0].y * inv + b0.y;
            of[2] = acc2[1].x * inv + b0.z; of[3] = acc2[1].y * inv + b0.w;
            of[4] = acc2[2].x * inv + b1.x; of[5] = acc2[2].y * inv + b1.y;
            of[6] = acc2[3].x * inv + b1.z; of[7] = acc2[3].y * inv + b1.w;
#pragma unroll
            for (int j = 0; j < 4; j++) {
                bnsum2[j].x += of[2 * j];     bnsum2[j].y += of[2 * j + 1];
                bnsq2[j].x += of[2 * j] * of[2 * j];
                bnsq2[j].y += of[2 * j + 1] * of[2 * j + 1];
            }
            float* ob = out + (size_t)n * 128 + colb;
            *(float4*)ob = make_float4(of[0], of[1], of[2], of[3]);
            *(float4*)(ob + 4) = make_float4(of[4], of[5], of[6], of[7]);
        }
    }

    __syncthreads();
    if (lane < 16) {
#pragma unroll
        for (int j = 0; j < 4; j++) {
            wbase[colb + 2 * j] = bnsum2[j].x;
            wbase[colb + 2 * j + 1] = bnsum2[j].y;
        }
    }
    __syncthreads();
    if (t < 128) {
        int sh = (blockIdx.x & (NS - 1)) * 256;
        float s = sw_lds[0][t] + sw_lds[1][t] + sw_lds[2][t] + sw_lds[3][t];
        atomicAdd(&bnsh[sh + t], s);
    }
    __syncthreads();
    if (lane < 16) {
#pragma unroll
        for (int j = 0; j < 4; j++) {
            wbase[colb + 2 * j] = bnsq2[j].x;
            wbase[colb + 2 * j + 1] = bnsq2[j].y;
        }
    }
    __syncthreads();
    if (t < 128) {
        int sh = (blockIdx.x & (NS - 1)) * 256;
        float q = sw_lds[0][t] + sw_lds[1][t] + sw_lds[2][t] + sw_lds[3][t];
        atomicAdd(&bnsh[sh + 128 + t], q);
    }
}

// ---------- final BN+ReLU on f32 output, stats from shadows ----------
__global__ __launch_bounds__(256) void bn_apply_final_kernel(float* __restrict__ x,
                                                             const float* __restrict__ bnsh,
                                                             const float* __restrict__ gamma,
                                                             const float* __restrict__ beta,
                                                             int Nn) {
    int t = threadIdx.x;
    int col = t & 127;
    float s = 0.f, q = 0.f;
#pragma unroll
    for (int sh = 0; sh < NS; sh++) { s += bnsh[sh * 256 + col]; q += bnsh[sh * 256 + 128 + col]; }
    float mu = s / (float)Nn;
    float var = q / (float)Nn - mu * mu;
    float sc = rsqrtf(var + EPS_BN) * gamma[col];
    float sh_ = beta[col] - mu * sc;
    int r0 = blockIdx.x * 2 + (t >> 7);
    int rs = gridDim.x * 2;
    for (int r = r0; r < Nn; r += rs) {
        size_t idx = (size_t)r * 128 + col;
        x[idx] = fmaxf(x[idx] * sc + sh_, 0.f);
    }
}

extern "C" void kernel_launch(void* const* d_in, const int* in_sizes, int n_in,
                              void* d_out, int out_size, void* d_ws, size_t ws_size,
                              hipStream_t stream) {
    const float* x        = (const float*)d_in[0];
    const void*  ei       = d_in[1];
    const float* W1       = (const float*)d_in[2];
    const float* att_src1 = (const float*)d_in[3];
    const float* att_dst1 = (const float*)d_in[4];
    const float* b1       = (const float*)d_in[5];
    const float* g1       = (const float*)d_in[6];
    const float* be1      = (const float*)d_in[7];
    const float* W2       = (const float*)d_in[8];
    const float* att_src2 = (const float*)d_in[9];
    const float* att_dst2 = (const float*)d_in[10];
    const float* b2       = (const float*)d_in[11];
    const float* g2       = (const float*)d_in[12];
    const float* be2      = (const float*)d_in[13];

    const int Nn = in_sizes[0] / IN_DIM;  // 50000
    const int E_ = in_sizes[1] / 2;       // 800000
    const int gb = (Nn + 127) / 128;      // 391 row-blocks
    const int Mpad = gb * 128 + 128;

    char* ws = (char*)d_ws;
    size_t o = 0;
    auto alloc = [&](size_t bytes) {
        size_t r = o;
        o += (bytes + 255) & ~(size_t)255;
        return r;
    };
    size_t z0 = o;
    int*   deg   = (int*)(ws + alloc((size_t)Nn * 4));
    float* as1   = (float*)(ws + alloc((size_t)Nn * 2 * 4));
    float* ad1   = (float*)(ws + alloc((size_t)Nn * 2 * 4));
    float* as2   = (float*)(ws + alloc((size_t)Nn * 4));
    float* ad2   = (float*)(ws + alloc((size_t)Nn * 4));
    float* bn1sh = (float*)(ws + alloc((size_t)NS * 512 * 4));
    float* bn2sh = (float*)(ws + alloc((size_t)NS * 256 * 4));
    size_t z1 = o;
    int*   rowptr = (int*)(ws + alloc((size_t)(Nn + 1) * 4));
    int*   ctr    = (int*)(ws + alloc((size_t)Nn * 4));
    int*   srcs   = (int*)(ws + alloc((size_t)E_ * 4));
    unsigned short* Wt1  = (unsigned short*)(ws + alloc((size_t)256 * 256 * 2));
    unsigned short* Wt2  = (unsigned short*)(ws + alloc((size_t)128 * 256 * 2));
    unsigned short* xb   = (unsigned short*)(ws + alloc((size_t)Mpad * 256 * 2));
    unsigned short* x2b0 = (unsigned short*)(ws + alloc((size_t)Nn * 256 * 2));
    unsigned short* h1b  = (unsigned short*)(ws + alloc((size_t)Nn * 256 * 2));
    unsigned short* h2b  = (unsigned short*)(ws + alloc((size_t)Nn * 128 * 2));
    float* outf = (float*)d_out;

    hipMemsetAsync(ws + z0, 0, z1 - z0, stream);

    long long n8 = (long long)Nn * 256 / 8;
    int eb = (E_ + 255) / 256;   // 3125
    int nsb = (Nn + 255) / 256;  // 196

    // K1: x-cast + Wt transposes + degree count (homogeneous, one launch)
    {
        long long grid = (n8 + 255) / 256 + 256 + 128 + eb;
        prep_count_kernel<<<(int)grid, 256, 0, stream>>>(x, xb, n8, W1, Wt1, W2, Wt2,
                                                         ei, deg, E_);
    }
    scan_kernel<<<nsb, 256, 0, stream>>>(deg, rowptr, ctr, Nn, nsb);
    scatter_kernel<<<eb, 256, 0, stream>>>(ei, ctr, srcs, E_);

    const int agg_blocks = 2048;  // persistent grid-stride

    // layer 1
    gemm_mfma_kernel<256, 2, false><<<dim3(gb, 4), 256, 0, stream>>>(
        xb, Wt1, h1b, att_src1, att_dst1, as1, ad1, Nn, nullptr, nullptr, nullptr);
    aggregate1_kernel<<<agg_blocks, 256, 0, stream>>>(h1b, rowptr, srcs, as1, ad1, b1, x2b0,
                                                      bn1sh, Nn);

    // layer 2 (BN1-apply+ReLU fused into GEMM2's A reg-staging)
    gemm_mfma_kernel<128, 1, true><<<dim3(gb, 2), 256, 0, stream>>>(
        x2b0, Wt2, h2b, att_src2, att_dst2, as2, ad2, Nn, bn1sh, g1, be1);
    aggregate2_kernel<<<agg_blocks, 256, 0, stream>>>(h2b, rowptr, srcs, as2, ad2, b2, outf,
                                                      bn2sh, Nn);
    bn_apply_final_kernel<<<512, 256, 0, stream>>>(outf, bn2sh, g2, be2, Nn);
}

// Round 14
// 291.985 us; speedup vs baseline: 1.1135x; 1.0755x over previous
//
#include <hip/hip_runtime.h>
#include <math.h>

#define IN_DIM 256
#define EPS_BN 1e-5f
#define NS 16  // BN shadow-copy count (atomic contention spreader)

typedef __attribute__((ext_vector_type(8))) short short8v;  // 8 bf16 (4 VGPRs)
typedef __attribute__((ext_vector_type(4))) float f32x4;    // MFMA C/D

__device__ __forceinline__ float lrelu(float v) { return v > 0.f ? v : 0.2f * v; }

__device__ __forceinline__ unsigned short f2bf(float f) {
    unsigned int u = __float_as_uint(f);
    u += 0x7fffu + ((u >> 16) & 1u);
    return (unsigned short)(u >> 16);
}
__device__ __forceinline__ float bf2f(unsigned short s) {
    return __uint_as_float((unsigned int)s << 16);
}

// packed bf16-pair FMA: a.x += w*lo(pw), a.y += w*hi(pw)
__device__ __forceinline__ void bfma(float2& a, unsigned int pw, float w) {
    a.x = fmaf(__uint_as_float(pw << 16), w, a.x);
    a.y = fmaf(__uint_as_float(pw & 0xffff0000u), w, a.y);
}

__device__ __forceinline__ void gld16(const void* g, void* l) {
    __builtin_amdgcn_global_load_lds((const __attribute__((address_space(1))) void*)g,
                                     (__attribute__((address_space(3))) void*)l, 16, 0, 0);
}

__device__ __forceinline__ int edge_at(const void* ei, int is64, long long i) {
    if (is64) return (int)((const long long*)ei)[i];
    return ((const int*)ei)[i];
}

// ---------- combined prep: bf16(x), Wt1, Wt2, edge-dtype detect — one launch ----------
__global__ __launch_bounds__(256) void prep_kernel(const float* __restrict__ x,
                                                   unsigned short* __restrict__ xb, long long n8,
                                                   const float* __restrict__ W1,
                                                   unsigned short* __restrict__ Wt1,
                                                   const float* __restrict__ W2,
                                                   unsigned short* __restrict__ Wt2,
                                                   const unsigned int* __restrict__ eiw,
                                                   int* __restrict__ flag, long long nwords) {
    __shared__ int nz;
    long long nbx = (n8 + 255) / 256;
    long long b = blockIdx.x;
    if (b < nbx) {
        long long i = b * 256 + threadIdx.x;
        if (i < n8) {
            const float4* p = (const float4*)(x + i * 8);
            float4 v0 = p[0], v1 = p[1];
            ushort4 o0, o1;
            o0.x = f2bf(v0.x); o0.y = f2bf(v0.y); o0.z = f2bf(v0.z); o0.w = f2bf(v0.w);
            o1.x = f2bf(v1.x); o1.y = f2bf(v1.y); o1.z = f2bf(v1.z); o1.w = f2bf(v1.w);
            *(ushort4*)(xb + i * 8) = o0;
            *(ushort4*)(xb + i * 8 + 4) = o1;
        }
        return;
    }
    b -= nbx;
    if (b < 256) {  // Wt1[c][k] = bf16(W1[k][c]), 256x256
        int idx = (int)b * 256 + threadIdx.x;
        int c = idx >> 8, k = idx & 255;
        Wt1[idx] = f2bf(W1[(long long)k * 256 + c]);
        return;
    }
    b -= 256;
    if (b < 128) {  // Wt2[c][k] = bf16(W2[k][c]), 128x256
        int idx = (int)b * 256 + threadIdx.x;
        int c = idx >> 8, k = idx & 255;
        Wt2[idx] = f2bf(W2[(long long)k * 128 + c]);
        return;
    }
    // last block: int32-vs-int64 detection (odd 32-bit words all zero -> int64)
    if (threadIdx.x == 0) nz = 0;
    __syncthreads();
    int cnt = 0;
    for (int i = 0; i < 4; i++) {
        long long idx = 2LL * (threadIdx.x + i * 256) + 1;
        if (idx < nwords && eiw[idx] != 0u) cnt++;
    }
    if (cnt) atomicAdd(&nz, 1);
    __syncthreads();
    if (threadIdx.x == 0) flag[0] = (nz == 0) ? 1 : 0;
}

// ---------- CSR build ----------
__global__ void count_deg_kernel(const void* __restrict__ ei, const int* __restrict__ flag,
                                 int* __restrict__ deg, int E_) {
    int is64 = flag[0];
    int i = blockIdx.x * 256 + threadIdx.x;
    if (i < E_) {
        int d = edge_at(ei, is64, (long long)E_ + i);
        atomicAdd(&deg[d], 1);
    }
}

__global__ __launch_bounds__(256) void scan_partial_kernel(const int* __restrict__ deg,
                                                           int* __restrict__ bsum, int n) {
    __shared__ int sh[256];
    int t = threadIdx.x;
    int i = blockIdx.x * 256 + t;
    sh[t] = (i < n) ? deg[i] : 0;
    __syncthreads();
    for (int off = 128; off >= 1; off >>= 1) {
        if (t < off) sh[t] += sh[t + off];
        __syncthreads();
    }
    if (t == 0) bsum[blockIdx.x] = sh[0];
}

__global__ __launch_bounds__(256) void scan_write_kernel(const int* __restrict__ deg,
                                                         const int* __restrict__ bsum,
                                                         int* __restrict__ rowptr,
                                                         int* __restrict__ ctr, int n, int nb) {
    __shared__ int sh[256];
    __shared__ int base_sh;
    int t = threadIdx.x;
    int b = blockIdx.x;
    sh[t] = (t < b) ? bsum[t] : 0;
    __syncthreads();
    for (int off = 128; off >= 1; off >>= 1) {
        if (t < off) sh[t] += sh[t + off];
        __syncthreads();
    }
    if (t == 0) base_sh = sh[0];
    __syncthreads();
    int i = b * 256 + t;
    int d = (i < n) ? deg[i] : 0;
    sh[t] = d;
    __syncthreads();
    for (int off = 1; off < 256; off <<= 1) {
        int u = (t >= off) ? sh[t - off] : 0;
        __syncthreads();
        sh[t] += u;
        __syncthreads();
    }
    if (i < n) {
        int v = base_sh + sh[t] - d;
        rowptr[i] = v;
        ctr[i] = v;
    }
    if (b == nb - 1 && t == 255) rowptr[n] = base_sh + sh[255];
}

__global__ void scatter_kernel(const void* __restrict__ ei, const int* __restrict__ flag,
                               int* __restrict__ ctr, int* __restrict__ srcs, int E_) {
    int is64 = flag[0];
    int i = blockIdx.x * 256 + threadIdx.x;
    if (i < E_) {
        int s = edge_at(ei, is64, i);
        int d = edge_at(ei, is64, (long long)E_ + i);
        int pos = atomicAdd(&ctr[d], 1);
        srcs[pos] = s;
    }
}

// ---------- MFMA bf16 GEMM + fused attn-coef epilogue (+ optional fused BN on A) ----------
template <int NCOL, int NH, bool FUSEBN>
__global__ __launch_bounds__(256) void gemm_mfma_kernel(const unsigned short* __restrict__ Ab,
                                                        const unsigned short* __restrict__ Wt,
                                                        unsigned short* __restrict__ C,
                                                        const float* __restrict__ att_s,
                                                        const float* __restrict__ att_d,
                                                        float* __restrict__ a_s,
                                                        float* __restrict__ a_d, int M,
                                                        const float* __restrict__ bnsh,
                                                        const float* __restrict__ gamma,
                                                        const float* __restrict__ beta) {
    __shared__ unsigned short B_lds[64 * 256];   // 32 KB
    __shared__ unsigned short A_lds[128 * 64];   // 16 KB
    __shared__ float scs[FUSEBN ? 256 : 1];
    __shared__ float shs[FUSEBN ? 256 : 1];
    const int t = threadIdx.x;
    const int w = t >> 6, l = t & 63;
    const int row0 = blockIdx.x * 128;
    const int col0 = blockIdx.y * 64;

    {
        const char* wb = (const char*)Wt + (size_t)col0 * 512;
#pragma unroll
        for (int it = 0; it < 8; ++it) {
            int q = w * 8 + it;
            int i = q * 64 + l;
            int r = i >> 5;
            int cs = (i & 31) ^ (r & 7);
            gld16(wb + (size_t)r * 512 + cs * 16, (char*)B_lds + q * 1024);
        }
    }

    short8v nxt[4];
    const char* ab = (const char*)Ab + (size_t)row0 * 512;

    if (FUSEBN) {
        {
            int c = t;
            float s = 0.f, q = 0.f;
#pragma unroll
            for (int sh = 0; sh < NS; sh++) { s += bnsh[sh * 512 + c]; q += bnsh[sh * 512 + 256 + c]; }
            float invN = 1.f / (float)M;
            float mu = s * invN;
            float var = q * invN - mu * mu;
            float sc = rsqrtf(var + EPS_BN) * gamma[c];
            scs[c] = sc;
            shs[c] = beta[c] - mu * sc;
        }
#pragma unroll
        for (int it = 0; it < 4; ++it) {
            int i = it * 256 + t;
            int r = i >> 3, g = i & 7;
            int gr = row0 + r;
            nxt[it] = (gr < M) ? *(const short8v*)(Ab + (size_t)gr * 256 + g * 8)
                               : (short8v)(short)0;
        }
        __syncthreads();
#pragma unroll
        for (int it = 0; it < 4; ++it) {
            int i = it * 256 + t;
            int r = i >> 3, g = i & 7;
            int kb = g * 8;
            float4 s0 = *(const float4*)&scs[kb], s1 = *(const float4*)&scs[kb + 4];
            float4 h0 = *(const float4*)&shs[kb], h1 = *(const float4*)&shs[kb + 4];
            short8v v = nxt[it];
            short8v ov;
            ov[0] = (short)f2bf(fmaxf(bf2f((unsigned short)v[0]) * s0.x + h0.x, 0.f));
            ov[1] = (short)f2bf(fmaxf(bf2f((unsigned short)v[1]) * s0.y + h0.y, 0.f));
            ov[2] = (short)f2bf(fmaxf(bf2f((unsigned short)v[2]) * s0.z + h0.z, 0.f));
            ov[3] = (short)f2bf(fmaxf(bf2f((unsigned short)v[3]) * s0.w + h0.w, 0.f));
            ov[4] = (short)f2bf(fmaxf(bf2f((unsigned short)v[4]) * s1.x + h1.x, 0.f));
            ov[5] = (short)f2bf(fmaxf(bf2f((unsigned short)v[5]) * s1.y + h1.y, 0.f));
            ov[6] = (short)f2bf(fmaxf(bf2f((unsigned short)v[6]) * s1.z + h1.z, 0.f));
            ov[7] = (short)f2bf(fmaxf(bf2f((unsigned short)v[7]) * s1.w + h1.w, 0.f));
            *(short8v*)((char*)A_lds + r * 128 + ((g ^ (r & 7)) << 4)) = ov;
        }
    } else {
#pragma unroll
        for (int it = 0; it < 4; ++it) {
            int q = w * 4 + it;
            int i = q * 64 + l;
            int r = i >> 3;
            int cs = (i & 7) ^ (r & 7);
            gld16(ab + (size_t)r * 512 + cs * 16, (char*)A_lds + q * 1024);
        }
    }
    __syncthreads();

    const int rl = l & 15, kg = l >> 4;
    f32x4 acc0[4], acc1[4];
#pragma unroll
    for (int i = 0; i < 4; ++i) { acc0[i] = (f32x4)(0.f); acc1[i] = (f32x4)(0.f); }

    const int ar0 = w * 32 + rl, ar1 = ar0 + 16;
    const int aswz = (ar0 & 7) << 4;

    for (int c = 0; c < 4; ++c) {
        if (FUSEBN && c < 3) {
#pragma unroll
            for (int it = 0; it < 4; ++it) {
                int i = it * 256 + t;
                int r = i >> 3, g = i & 7;
                int gr = row0 + r;
                nxt[it] = (gr < M) ? *(const short8v*)(Ab + (size_t)gr * 256 + (c + 1) * 64 + g * 8)
                                   : (short8v)(short)0;
            }
        }
#pragma unroll
        for (int s = 0; s < 2; ++s) {
            short8v a0 = *(const short8v*)((const char*)A_lds +
                          ((ar0 * 128 + s * 64 + kg * 16) ^ aswz));
            short8v a1 = *(const short8v*)((const char*)A_lds +
                          ((ar1 * 128 + s * 64 + kg * 16) ^ aswz));
#pragma unroll
            for (int ct = 0; ct < 4; ++ct) {
                int br = ct * 16 + rl;
                short8v bfr = *(const short8v*)((const char*)B_lds +
                               ((br * 512 + c * 128 + s * 64 + kg * 16) ^ ((br & 7) << 4)));
                acc0[ct] = __builtin_amdgcn_mfma_f32_16x16x32_bf16(a0, bfr, acc0[ct], 0, 0, 0);
                acc1[ct] = __builtin_amdgcn_mfma_f32_16x16x32_bf16(a1, bfr, acc1[ct], 0, 0, 0);
            }
        }
        __syncthreads();
        if (c < 3) {
            if (FUSEBN) {
#pragma unroll
                for (int it = 0; it < 4; ++it) {
                    int i = it * 256 + t;
                    int r = i >> 3, g = i & 7;
                    int kb = (c + 1) * 64 + g * 8;
                    float4 s0 = *(const float4*)&scs[kb], s1 = *(const float4*)&scs[kb + 4];
                    float4 h0 = *(const float4*)&shs[kb], h1 = *(const float4*)&shs[kb + 4];
                    short8v v = nxt[it];
                    short8v ov;
                    ov[0] = (short)f2bf(fmaxf(bf2f((unsigned short)v[0]) * s0.x + h0.x, 0.f));
                    ov[1] = (short)f2bf(fmaxf(bf2f((unsigned short)v[1]) * s0.y + h0.y, 0.f));
                    ov[2] = (short)f2bf(fmaxf(bf2f((unsigned short)v[2]) * s0.z + h0.z, 0.f));
                    ov[3] = (short)f2bf(fmaxf(bf2f((unsigned short)v[3]) * s0.w + h0.w, 0.f));
                    ov[4] = (short)f2bf(fmaxf(bf2f((unsigned short)v[4]) * s1.x + h1.x, 0.f));
                    ov[5] = (short)f2bf(fmaxf(bf2f((unsigned short)v[5]) * s1.y + h1.y, 0.f));
                    ov[6] = (short)f2bf(fmaxf(bf2f((unsigned short)v[6]) * s1.z + h1.z, 0.f));
                    ov[7] = (short)f2bf(fmaxf(bf2f((unsigned short)v[7]) * s1.w + h1.w, 0.f));
                    *(short8v*)((char*)A_lds + r * 128 + ((g ^ (r & 7)) << 4)) = ov;
                }
            } else {
#pragma unroll
                for (int it = 0; it < 4; ++it) {
                    int q = w * 4 + it;
                    int i = q * 64 + l;
                    int r = i >> 3;
                    int cs = (i & 7) ^ (r & 7);
                    gld16(ab + (size_t)r * 512 + (c + 1) * 128 + cs * 16, (char*)A_lds + q * 1024);
                }
            }
            __syncthreads();
        }
    }

#pragma unroll
    for (int ct = 0; ct < 4; ++ct) {
#pragma unroll
        for (int r = 0; r < 4; ++r) {
            int gr0 = row0 + w * 32 + kg * 4 + r;
            if (gr0 < M) C[(long long)gr0 * NCOL + col0 + ct * 16 + rl] = f2bf(acc0[ct][r]);
            int gr1 = gr0 + 16;
            if (gr1 < M) C[(long long)gr1 * NCOL + col0 + ct * 16 + rl] = f2bf(acc1[ct][r]);
        }
    }

    float asp0[4] = {}, adp0[4] = {}, asp1[4] = {}, adp1[4] = {};
#pragma unroll
    for (int ct = 0; ct < 4; ++ct) {
        int col = col0 + ct * 16 + rl;
        float vs = att_s[col], vd = att_d[col];
#pragma unroll
        for (int r = 0; r < 4; ++r) {
            asp0[r] += acc0[ct][r] * vs; adp0[r] += acc0[ct][r] * vd;
            asp1[r] += acc1[ct][r] * vs; adp1[r] += acc1[ct][r] * vd;
        }
    }
#pragma unroll
    for (int off = 1; off < 16; off <<= 1) {
#pragma unroll
        for (int r = 0; r < 4; ++r) {
            asp0[r] += __shfl_xor(asp0[r], off);
            adp0[r] += __shfl_xor(adp0[r], off);
            asp1[r] += __shfl_xor(asp1[r], off);
            adp1[r] += __shfl_xor(adp1[r], off);
        }
    }
    if (rl == 0) {
        int head = (NH == 2) ? (col0 >> 7) : 0;
#pragma unroll
        for (int r = 0; r < 4; ++r) {
            int gr0 = row0 + w * 32 + kg * 4 + r;
            if (gr0 < M) {
                atomicAdd(&a_s[gr0 * NH + head], asp0[r]);
                atomicAdd(&a_d[gr0 * NH + head], adp0[r]);
            }
            int gr1 = gr0 + 16;
            if (gr1 < M) {
                atomicAdd(&a_s[gr1 * NH + head], asp1[r]);
                atomicAdd(&a_d[gr1 * NH + head], adp1[r]);
            }
        }
    }
}

// ---------- aggregate layer 1: persistent waves + register BN partials + packed FMA ----------
__global__ __launch_bounds__(256) void aggregate1_kernel(const unsigned short* __restrict__ h,
                                                         const int* __restrict__ rowptr,
                                                         const int* __restrict__ srcs,
                                                         const float* __restrict__ a_s,
                                                         const float* __restrict__ a_d,
                                                         const float* __restrict__ bias,
                                                         unsigned short* __restrict__ out,
                                                         float* __restrict__ bnsh, int Nn) {
    __shared__ float sw_lds[4][256];
    const int t = threadIdx.x;
    const int wid = t >> 6, lane = t & 63;
    const int hh = (lane >> 4) & 1;
    const int eb = lane >> 5;
    const int colb = (lane & 31) * 8;
    float* wbase = sw_lds[wid];
    float2 bnsum2[4] = {}, bnsq2[4] = {};
    const int stride = gridDim.x * 4;

    for (int n = blockIdx.x * 4 + wid; n < Nn; n += stride) {
        int beg = rowptr[n], end = rowptr[n + 1];
        float2 adv = *(const float2*)&a_d[(size_t)n * 2];
        float ad0 = adv.x, ad1 = adv.y;
        float2 acc2[4] = {};
        float den = 0.f, m0 = -1e30f, m1 = -1e30f;

        for (int cb = beg; cb < end; cb += 64) {
            int cnt = end - cb; if (cnt > 64) cnt = 64;
            float e0 = -1e30f, e1 = -1e30f;
            int s_l = 0;
            if (lane < cnt) {
                s_l = srcs[cb + lane];
                float2 av = *(const float2*)&a_s[(size_t)s_l * 2];
                e0 = lrelu(av.x + ad0);
                e1 = lrelu(av.y + ad1);
            }
            float cm0 = e0, cm1 = e1;
            for (int off = 32; off >= 1; off >>= 1) {
                cm0 = fmaxf(cm0, __shfl_xor(cm0, off));
                cm1 = fmaxf(cm1, __shfl_xor(cm1, off));
            }
            if (cm0 > m0 || cm1 > m1) {
                float f0 = (cm0 > m0) ? __expf(m0 - cm0) : 1.f;
                float f1 = (cm1 > m1) ? __expf(m1 - cm1) : 1.f;
                m0 = fmaxf(m0, cm0); m1 = fmaxf(m1, cm1);
                float fo = hh ? f1 : f0;
#pragma unroll
                for (int j = 0; j < 4; j++) { acc2[j].x *= fo; acc2[j].y *= fo; }
                den *= fo;
            }
            if (lane < cnt) {
                *(float2*)&wbase[lane * 2] = make_float2(__int_as_float(s_l), __expf(e0 - m0));
                *(float2*)&wbase[128 + lane * 2] = make_float2(__int_as_float(s_l), __expf(e1 - m1));
            }
            int c = 0;
            for (; c + 8 <= cnt; c += 8) {
                float2 sw0 = *(const float2*)&wbase[hh * 128 + (c + eb) * 2];
                float2 sw1 = *(const float2*)&wbase[hh * 128 + (c + 2 + eb) * 2];
                float2 sw2 = *(const float2*)&wbase[hh * 128 + (c + 4 + eb) * 2];
                float2 sw3 = *(const float2*)&wbase[hh * 128 + (c + 6 + eb) * 2];
                uint4 p0 = *(const uint4*)(h + ((size_t)__float_as_int(sw0.x) << 8) + colb);
                uint4 p1 = *(const uint4*)(h + ((size_t)__float_as_int(sw1.x) << 8) + colb);
                uint4 p2 = *(const uint4*)(h + ((size_t)__float_as_int(sw2.x) << 8) + colb);
                uint4 p3 = *(const uint4*)(h + ((size_t)__float_as_int(sw3.x) << 8) + colb);
                den += sw0.y + sw1.y + sw2.y + sw3.y;
                bfma(acc2[0], p0.x, sw0.y); bfma(acc2[1], p0.y, sw0.y);
                bfma(acc2[2], p0.z, sw0.y); bfma(acc2[3], p0.w, sw0.y);
                bfma(acc2[0], p1.x, sw1.y); bfma(acc2[1], p1.y, sw1.y);
                bfma(acc2[2], p1.z, sw1.y); bfma(acc2[3], p1.w, sw1.y);
                bfma(acc2[0], p2.x, sw2.y); bfma(acc2[1], p2.y, sw2.y);
                bfma(acc2[2], p2.z, sw2.y); bfma(acc2[3], p2.w, sw2.y);
                bfma(acc2[0], p3.x, sw3.y); bfma(acc2[1], p3.y, sw3.y);
                bfma(acc2[2], p3.z, sw3.y); bfma(acc2[3], p3.w, sw3.y);
            }
            for (; c + 4 <= cnt; c += 4) {
                float2 sw0 = *(const float2*)&wbase[hh * 128 + (c + eb) * 2];
                float2 sw1 = *(const float2*)&wbase[hh * 128 + (c + 2 + eb) * 2];
                uint4 p0 = *(const uint4*)(h + ((size_t)__float_as_int(sw0.x) << 8) + colb);
                uint4 p1 = *(const uint4*)(h + ((size_t)__float_as_int(sw1.x) << 8) + colb);
                den += sw0.y + sw1.y;
                bfma(acc2[0], p0.x, sw0.y); bfma(acc2[1], p0.y, sw0.y);
                bfma(acc2[2], p0.z, sw0.y); bfma(acc2[3], p0.w, sw0.y);
                bfma(acc2[0], p1.x, sw1.y); bfma(acc2[1], p1.y, sw1.y);
                bfma(acc2[2], p1.z, sw1.y); bfma(acc2[3], p1.w, sw1.y);
            }
            for (; c < cnt; c += 2) {
                int e = c + eb;
                if (e < cnt) {
                    float2 sw0 = *(const float2*)&wbase[hh * 128 + e * 2];
                    uint4 p0 = *(const uint4*)(h + ((size_t)__float_as_int(sw0.x) << 8) + colb);
                    den += sw0.y;
                    bfma(acc2[0], p0.x, sw0.y); bfma(acc2[1], p0.y, sw0.y);
                    bfma(acc2[2], p0.z, sw0.y); bfma(acc2[3], p0.w, sw0.y);
                }
            }
        }
        den += __shfl_xor(den, 32);
#pragma unroll
        for (int j = 0; j < 4; j++) {
            acc2[j].x += __shfl_xor(acc2[j].x, 32);
            acc2[j].y += __shfl_xor(acc2[j].y, 32);
        }
        if (lane < 32) {
            float inv = 1.f / (den + 1e-16f);
            float4 b0 = *(const float4*)&bias[colb];
            float4 b1 = *(const float4*)&bias[colb + 4];
            float of[8];
            of[0] = acc2[0].x * inv + b0.x; of[1] = acc2[0].y * inv + b0.y;
            of[2] = acc2[1].x * inv + b0.z; of[3] = acc2[1].y * inv + b0.w;
            of[4] = acc2[2].x * inv + b1.x; of[5] = acc2[2].y * inv + b1.y;
            of[6] = acc2[3].x * inv + b1.z; of[7] = acc2[3].y * inv + b1.w;
            short8v o;
#pragma unroll
            for (int j = 0; j < 4; j++) {
                o[2 * j] = (short)f2bf(of[2 * j]);
                o[2 * j + 1] = (short)f2bf(of[2 * j + 1]);
                bnsum2[j].x += of[2 * j];     bnsum2[j].y += of[2 * j + 1];
                bnsq2[j].x += of[2 * j] * of[2 * j];
                bnsq2[j].y += of[2 * j + 1] * of[2 * j + 1];
            }
            *(short8v*)(out + ((size_t)n << 8) + colb) = o;
        }
    }

    // once-per-block BN reduction (reuse sw_lds)
    __syncthreads();
    if (lane < 32) {
#pragma unroll
        for (int j = 0; j < 4; j++) {
            wbase[colb + 2 * j] = bnsum2[j].x;
            wbase[colb + 2 * j + 1] = bnsum2[j].y;
        }
    }
    __syncthreads();
    {
        int sh = (blockIdx.x & (NS - 1)) * 512;
        float s = sw_lds[0][t] + sw_lds[1][t] + sw_lds[2][t] + sw_lds[3][t];
        atomicAdd(&bnsh[sh + t], s);
    }
    __syncthreads();
    if (lane < 32) {
#pragma unroll
        for (int j = 0; j < 4; j++) {
            wbase[colb + 2 * j] = bnsq2[j].x;
            wbase[colb + 2 * j + 1] = bnsq2[j].y;
        }
    }
    __syncthreads();
    {
        int sh = (blockIdx.x & (NS - 1)) * 512;
        float q = sw_lds[0][t] + sw_lds[1][t] + sw_lds[2][t] + sw_lds[3][t];
        atomicAdd(&bnsh[sh + 256 + t], q);
    }
}

// ---------- aggregate layer 2: persistent waves + register BN partials + packed FMA ----------
__global__ __launch_bounds__(256) void aggregate2_kernel(const unsigned short* __restrict__ h,
                                                         const int* __restrict__ rowptr,
                                                         const int* __restrict__ srcs,
                                                         const float* __restrict__ a_s,
                                                         const float* __restrict__ a_d,
                                                         const float* __restrict__ bias,
                                                         float* __restrict__ out,
                                                         float* __restrict__ bnsh, int Nn) {
    __shared__ float sw_lds[4][128];
    const int t = threadIdx.x;
    const int wid = t >> 6, lane = t & 63;
    const int eo = lane >> 4;
    const int colb = (lane & 15) * 8;
    float* wbase = sw_lds[wid];
    float2 bnsum2[4] = {}, bnsq2[4] = {};
    const int stride = gridDim.x * 4;

    for (int n = blockIdx.x * 4 + wid; n < Nn; n += stride) {
        int beg = rowptr[n], end = rowptr[n + 1];
        float ad = a_d[n];
        float2 acc2[4] = {};
        float den = 0.f, m = -1e30f;

        for (int cb = beg; cb < end; cb += 64) {
            int cnt = end - cb; if (cnt > 64) cnt = 64;
            float e_ = -1e30f;
            int s_l = 0;
            if (lane < cnt) {
                s_l = srcs[cb + lane];
                e_ = lrelu(a_s[s_l] + ad);
            }
            float cm = e_;
            for (int off = 32; off >= 1; off >>= 1) cm = fmaxf(cm, __shfl_xor(cm, off));
            if (cm > m) {
                float f = __expf(m - cm);
                m = cm;
#pragma unroll
                for (int j = 0; j < 4; j++) { acc2[j].x *= f; acc2[j].y *= f; }
                den *= f;
            }
            if (lane < cnt)
                *(float2*)&wbase[lane * 2] = make_float2(__int_as_float(s_l), __expf(e_ - m));
            int c = 0;
            for (; c + 16 <= cnt; c += 16) {
                float2 sw0 = *(const float2*)&wbase[(c + eo) * 2];
                float2 sw1 = *(const float2*)&wbase[(c + 4 + eo) * 2];
                float2 sw2 = *(const float2*)&wbase[(c + 8 + eo) * 2];
                float2 sw3 = *(const float2*)&wbase[(c + 12 + eo) * 2];
                uint4 p0 = *(const uint4*)(h + ((size_t)__float_as_int(sw0.x) << 7) + colb);
                uint4 p1 = *(const uint4*)(h + ((size_t)__float_as_int(sw1.x) << 7) + colb);
                uint4 p2 = *(const uint4*)(h + ((size_t)__float_as_int(sw2.x) << 7) + colb);
                uint4 p3 = *(const uint4*)(h + ((size_t)__float_as_int(sw3.x) << 7) + colb);
                den += sw0.y + sw1.y + sw2.y + sw3.y;
                bfma(acc2[0], p0.x, sw0.y); bfma(acc2[1], p0.y, sw0.y);
                bfma(acc2[2], p0.z, sw0.y); bfma(acc2[3], p0.w, sw0.y);
                bfma(acc2[0], p1.x, sw1.y); bfma(acc2[1], p1.y, sw1.y);
                bfma(acc2[2], p1.z, sw1.y); bfma(acc2[3], p1.w, sw1.y);
                bfma(acc2[0], p2.x, sw2.y); bfma(acc2[1], p2.y, sw2.y);
                bfma(acc2[2], p2.z, sw2.y); bfma(acc2[3], p2.w, sw2.y);
                bfma(acc2[0], p3.x, sw3.y); bfma(acc2[1], p3.y, sw3.y);
                bfma(acc2[2], p3.z, sw3.y); bfma(acc2[3], p3.w, sw3.y);
            }
            for (; c + 8 <= cnt; c += 8) {
                float2 sw0 = *(const float2*)&wbase[(c + eo) * 2];
                float2 sw1 = *(const float2*)&wbase[(c + 4 + eo) * 2];
                uint4 p0 = *(const uint4*)(h + ((size_t)__float_as_int(sw0.x) << 7) + colb);
                uint4 p1 = *(const uint4*)(h + ((size_t)__float_as_int(sw1.x) << 7) + colb);
                den += sw0.y + sw1.y;
                bfma(acc2[0], p0.x, sw0.y); bfma(acc2[1], p0.y, sw0.y);
                bfma(acc2[2], p0.z, sw0.y); bfma(acc2[3], p0.w, sw0.y);
                bfma(acc2[0], p1.x, sw1.y); bfma(acc2[1], p1.y, sw1.y);
                bfma(acc2[2], p1.z, sw1.y); bfma(acc2[3], p1.w, sw1.y);
            }
            for (; c < cnt; c += 4) {
                int e = c + eo;
                if (e < cnt) {
                    float2 sw0 = *(const float2*)&wbase[e * 2];
                    uint4 p0 = *(const uint4*)(h + ((size_t)__float_as_int(sw0.x) << 7) + colb);
                    den += sw0.y;
                    bfma(acc2[0], p0.x, sw0.y); bfma(acc2[1], p0.y, sw0.y);
                    bfma(acc2[2], p0.z, sw0.y); bfma(acc2[3], p0.w, sw0.y);
                }
            }
        }
        den += __shfl_xor(den, 16);
        den += __shfl_xor(den, 32);
#pragma unroll
        for (int j = 0; j < 4; j++) {
            acc2[j].x += __shfl_xor(acc2[j].x, 16);
            acc2[j].x += __shfl_xor(acc2[j].x, 32);
            acc2[j].y += __shfl_xor(acc2[j].y, 16);
            acc2[j].y += __shfl_xor(acc2[j].y, 32);
        }
        if (lane < 16) {
            float inv = 1.f / (den + 1e-16f);
            float4 b0 = *(const float4*)&bias[colb];
            float4 b1 = *(const float4*)&bias[colb + 4];
            float of[8];
            of[0] = acc2[0].x * inv + b0.x; of[1] = acc2[0].y * inv + b0.y;
            of[2] = acc2[1].x * inv + b0.z; of[3] = acc2[1].y * inv + b0.w;
            of[4] = acc2[2].x * inv + b1.x; of[5] = acc2[2].y * inv + b1.y;
            of[6] = acc2[3].x * inv + b1.z; of[7] = acc2[3].y * inv + b1.w;
#pragma unroll
            for (int j = 0; j < 4; j++) {
                bnsum2[j].x += of[2 * j];     bnsum2[j].y += of[2 * j + 1];
                bnsq2[j].x += of[2 * j] * of[2 * j];
                bnsq2[j].y += of[2 * j + 1] * of[2 * j + 1];
            }
            float* ob = out + (size_t)n * 128 + colb;
            *(float4*)ob = make_float4(of[0], of[1], of[2], of[3]);
            *(float4*)(ob + 4) = make_float4(of[4], of[5], of[6], of[7]);
        }
    }

    __syncthreads();
    if (lane < 16) {
#pragma unroll
        for (int j = 0; j < 4; j++) {
            wbase[colb + 2 * j] = bnsum2[j].x;
            wbase[colb + 2 * j + 1] = bnsum2[j].y;
        }
    }
    __syncthreads();
    if (t < 128) {
        int sh = (blockIdx.x & (NS - 1)) * 256;
        float s = sw_lds[0][t] + sw_lds[1][t] + sw_lds[2][t] + sw_lds[3][t];
        atomicAdd(&bnsh[sh + t], s);
    }
    __syncthreads();
    if (lane < 16) {
#pragma unroll
        for (int j = 0; j < 4; j++) {
            wbase[colb + 2 * j] = bnsq2[j].x;
            wbase[colb + 2 * j + 1] = bnsq2[j].y;
        }
    }
    __syncthreads();
    if (t < 128) {
        int sh = (blockIdx.x & (NS - 1)) * 256;
        float q = sw_lds[0][t] + sw_lds[1][t] + sw_lds[2][t] + sw_lds[3][t];
        atomicAdd(&bnsh[sh + 128 + t], q);
    }
}

// ---------- final BN+ReLU on f32 output, stats from shadows ----------
__global__ __launch_bounds__(256) void bn_apply_final_kernel(float* __restrict__ x,
                                                             const float* __restrict__ bnsh,
                                                             const float* __restrict__ gamma,
                                                             const float* __restrict__ beta,
                                                             int Nn) {
    int t = threadIdx.x;
    int col = t & 127;
    float s = 0.f, q = 0.f;
#pragma unroll
    for (int sh = 0; sh < NS; sh++) { s += bnsh[sh * 256 + col]; q += bnsh[sh * 256 + 128 + col]; }
    float mu = s / (float)Nn;
    float var = q / (float)Nn - mu * mu;
    float sc = rsqrtf(var + EPS_BN) * gamma[col];
    float sh_ = beta[col] - mu * sc;
    int r0 = blockIdx.x * 2 + (t >> 7);
    int rs = gridDim.x * 2;
    for (int r = r0; r < Nn; r += rs) {
        size_t idx = (size_t)r * 128 + col;
        x[idx] = fmaxf(x[idx] * sc + sh_, 0.f);
    }
}

extern "C" void kernel_launch(void* const* d_in, const int* in_sizes, int n_in,
                              void* d_out, int out_size, void* d_ws, size_t ws_size,
                              hipStream_t stream) {
    const float* x        = (const float*)d_in[0];
    const void*  ei       = d_in[1];
    const float* W1       = (const float*)d_in[2];
    const float* att_src1 = (const float*)d_in[3];
    const float* att_dst1 = (const float*)d_in[4];
    const float* b1       = (const float*)d_in[5];
    const float* g1       = (const float*)d_in[6];
    const float* be1      = (const float*)d_in[7];
    const float* W2       = (const float*)d_in[8];
    const float* att_src2 = (const float*)d_in[9];
    const float* att_dst2 = (const float*)d_in[10];
    const float* b2       = (const float*)d_in[11];
    const float* g2       = (const float*)d_in[12];
    const float* be2      = (const float*)d_in[13];

    const int Nn = in_sizes[0] / IN_DIM;  // 50000
    const int E_ = in_sizes[1] / 2;       // 800000
    const int gb = (Nn + 127) / 128;      // 391 row-blocks
    const int Mpad = gb * 128 + 128;

    char* ws = (char*)d_ws;
    size_t o = 0;
    auto alloc = [&](size_t bytes) {
        size_t r = o;
        o += (bytes + 255) & ~(size_t)255;
        return r;
    };
    int* flag = (int*)(ws + alloc(4));
    size_t z0 = o;
    int*   deg   = (int*)(ws + alloc((size_t)Nn * 4));
    float* as1   = (float*)(ws + alloc((size_t)Nn * 2 * 4));
    float* ad1   = (float*)(ws + alloc((size_t)Nn * 2 * 4));
    float* as2   = (float*)(ws + alloc((size_t)Nn * 4));
    float* ad2   = (float*)(ws + alloc((size_t)Nn * 4));
    float* bn1sh = (float*)(ws + alloc((size_t)NS * 512 * 4));
    float* bn2sh = (float*)(ws + alloc((size_t)NS * 256 * 4));
    size_t z1 = o;
    int*   rowptr = (int*)(ws + alloc((size_t)(Nn + 1) * 4));
    int*   ctr    = (int*)(ws + alloc((size_t)Nn * 4));
    int*   srcs   = (int*)(ws + alloc((size_t)E_ * 4));
    int*   bsum   = (int*)(ws + alloc(256 * 4));
    unsigned short* Wt1  = (unsigned short*)(ws + alloc((size_t)256 * 256 * 2));
    unsigned short* Wt2  = (unsigned short*)(ws + alloc((size_t)128 * 256 * 2));
    unsigned short* xb   = (unsigned short*)(ws + alloc((size_t)Mpad * 256 * 2));
    unsigned short* x2b0 = (unsigned short*)(ws + alloc((size_t)Nn * 256 * 2));
    unsigned short* h1b  = (unsigned short*)(ws + alloc((size_t)Nn * 256 * 2));
    unsigned short* h2b  = (unsigned short*)(ws + alloc((size_t)Nn * 128 * 2));
    float* outf = (float*)d_out;

    hipMemsetAsync(ws + z0, 0, z1 - z0, stream);

    {
        long long n8 = (long long)Nn * 256 / 8;
        long long grid = (n8 + 255) / 256 + 256 + 128 + 1;
        prep_kernel<<<(int)grid, 256, 0, stream>>>(x, xb, n8, W1, Wt1, W2, Wt2,
                                                   (const unsigned int*)ei, flag,
                                                   (long long)2 * E_);
    }

    int eb = (E_ + 255) / 256;
    int nsb = (Nn + 255) / 256;  // <= 256
    count_deg_kernel<<<eb, 256, 0, stream>>>(ei, flag, deg, E_);
    scan_partial_kernel<<<nsb, 256, 0, stream>>>(deg, bsum, Nn);
    scan_write_kernel<<<nsb, 256, 0, stream>>>(deg, bsum, rowptr, ctr, Nn, nsb);
    scatter_kernel<<<eb, 256, 0, stream>>>(ei, flag, ctr, srcs, E_);

    const int agg_blocks = 2048;  // persistent grid-stride

    // layer 1
    gemm_mfma_kernel<256, 2, false><<<dim3(gb, 4), 256, 0, stream>>>(
        xb, Wt1, h1b, att_src1, att_dst1, as1, ad1, Nn, nullptr, nullptr, nullptr);
    aggregate1_kernel<<<agg_blocks, 256, 0, stream>>>(h1b, rowptr, srcs, as1, ad1, b1, x2b0,
                                                      bn1sh, Nn);

    // layer 2 (BN1-apply+ReLU fused into GEMM2's A reg-staging)
    gemm_mfma_kernel<128, 1, true><<<dim3(gb, 2), 256, 0, stream>>>(
        x2b0, Wt2, h2b, att_src2, att_dst2, as2, ad2, Nn, bn1sh, g1, be1);
    aggregate2_kernel<<<agg_blocks, 256, 0, stream>>>(h2b, rowptr, srcs, as2, ad2, b2, outf,
                                                      bn2sh, Nn);
    bn_apply_final_kernel<<<512, 256, 0, stream>>>(outf, bn2sh, g2, be2, Nn);
}